// Round 4
// baseline (394.555 us; speedup 1.0000x reference)
//
#include <hip/hip_runtime.h>
#include <hip/hip_bf16.h>
#include <stdint.h>

// ---------------------------------------------------------------------------
// Problem constants
// ---------------------------------------------------------------------------
#define NCLS   6
#define NATOMS 5
#define B_     64
#define P_     196
#define D_     768
#define H_     3072
#define SEQ    (NCLS + P_)        // 202
#define NPATCH (B_ * P_)          // 12544
#define NPAIR  (B_ * NCLS)        // 384

typedef unsigned short ushort_t;
typedef __attribute__((ext_vector_type(8))) short  bf16x8;
typedef __attribute__((ext_vector_type(4))) float  f32x4;

// ---------------------------------------------------------------------------
// Helpers
// ---------------------------------------------------------------------------
// fast tanh-form GELU (max abs err ~1e-3; threshold budget 3.98e-2)
__device__ __forceinline__ float gelu_fast(float x) {
    float x2 = x * x;
    float y  = x * (1.59576912f + 0.07135482f * x2);
    float e  = __expf(y);
    return x * e / (e + 1.0f);
}

__device__ __forceinline__ ushort_t f2bf(float f) {
    uint32_t u = __builtin_bit_cast(uint32_t, f);
    u = (u + 0x7fffu + ((u >> 16) & 1u)) >> 16;
    return (ushort_t)u;
}

__device__ __forceinline__ void gload16(const ushort_t* g, ushort_t* l) {
    __builtin_amdgcn_global_load_lds(
        (const __attribute__((address_space(1))) uint32_t*)g,
        (__attribute__((address_space(3))) uint32_t*)l,
        16, 0, 0);
}

// ---------------------------------------------------------------------------
// fp32 -> bf16 conversion kernels
// ---------------------------------------------------------------------------
__global__ void cvt4_kernel(const float* __restrict__ in, ushort_t* __restrict__ out, int n) {
    int i = (blockIdx.x * blockDim.x + threadIdx.x) * 4;
    if (i >= n) return;
    float4 v = *(const float4*)(in + i);
    ushort4 o;
    o.x = f2bf(v.x); o.y = f2bf(v.y); o.z = f2bf(v.z); o.w = f2bf(v.w);
    *(ushort4*)(out + i) = o;
}

__global__ void split_x_kernel(const float* __restrict__ x,
                               ushort_t* __restrict__ xp,
                               ushort_t* __restrict__ cls) {
    int i = (blockIdx.x * blockDim.x + threadIdx.x) * 4;
    const int total = B_ * SEQ * D_;
    if (i >= total) return;
    int row = i / D_;
    int col = i - row * D_;
    int b = row / SEQ, s = row - b * SEQ;
    float4 v = *(const float4*)(x + i);
    ushort4 o;
    o.x = f2bf(v.x); o.y = f2bf(v.y); o.z = f2bf(v.z); o.w = f2bf(v.w);
    if (s < NCLS) {
        *(ushort4*)(cls + (size_t)(b * NCLS + s) * D_ + col) = o;
    } else {
        *(ushort4*)(xp + (size_t)(b * P_ + (s - NCLS)) * D_ + col) = o;
    }
}

// ---------------------------------------------------------------------------
// Gate
// ---------------------------------------------------------------------------
__global__ void gate_kernel(const float* __restrict__ x, const float* __restrict__ gd,
                            int* __restrict__ src, int* __restrict__ dst,
                            float* __restrict__ wgt) {
    int r = blockIdx.x;
    int b = r / NCLS, n = r - b * NCLS;
    const float* xr = x + (size_t)(b * SEQ + n) * D_;
    const float* g  = gd + (size_t)n * D_;
    int lane = threadIdx.x;
    float s = 0.f;
    for (int k = lane; k < D_; k += 64) s += xr[k] * g[k];
    #pragma unroll
    for (int off = 32; off > 0; off >>= 1) s += __shfl_down(s, off, 64);
    if (lane == 0) {
        float logit = s;
        bool left = (logit >= 0.f);
        float p = 1.f / (1.f + expf(-logit));
        float w = left ? p : (1.f - p);
        const int LK[NCLS] = {3, 4, 8, 9, 13, 14};
        const int RK[NCLS] = {15, 20, 16, 21, 17, 22};
        int key = left ? LK[n] : RK[n];
        src[r] = key / NATOMS;
        dst[r] = key % NATOMS;
        wgt[r] = w;
    }
}

// ---------------------------------------------------------------------------
// Depth-2 counted-vmcnt pipelined GEMM, BK=32, four named LDS buffers.
//   C[m,n] = sum_k A[m,k] * B[n,k]   (B in N x K layout)
// 128x128 tile, 4 waves (2x2), 16x16x32 bf16 MFMA, global_load_lds (16B).
// Per K-tile: issue stage(t+2) -> s_waitcnt vmcnt(8) (2 tiles stay in
// flight; drains only tile t) -> barrier -> 16 MFMA.  BK=32 gives 64B LDS
// rows: even/odd rows alternate bank halves -> conflict-free b128 reads.
// ---------------------------------------------------------------------------

// stage a ROWS x 32 bf16 tile: chunk c = l*NT+tid -> LDS bytes [c*16, c*16+16)
// = row c/4, 16B-slot c&3.  LDS dest linear (wave-uniform base + lane*16).
template <int ROWS, int NT>
__device__ __forceinline__ void stage32(const ushort_t* __restrict__ gbase, int K,
                                        int k0, ushort_t* lds, int tid) {
    constexpr int LOADS = ROWS * 4 / NT;
    #pragma unroll
    for (int l = 0; l < LOADS; ++l) {
        int c = l * NT + tid;
        gload16(gbase + (size_t)(c >> 2) * K + k0 + ((c & 3) << 3),
                lds + (size_t)c * 8);
    }
}

template <int FM, int FN>
__device__ __forceinline__ void compute32(const ushort_t* sA, const ushort_t* sB,
                                          int arow0, int brow0, int lane,
                                          f32x4 (&acc)[FM][FN]) {
    const int frow = lane & 15;
    const int fcol = (lane >> 4) * 8;
    bf16x8 af[FM], bf[FN];
    #pragma unroll
    for (int mi = 0; mi < FM; ++mi)
        af[mi] = *(const bf16x8*)(sA + (size_t)(arow0 + mi * 16 + frow) * 32 + fcol);
    #pragma unroll
    for (int ni = 0; ni < FN; ++ni)
        bf[ni] = *(const bf16x8*)(sB + (size_t)(brow0 + ni * 16 + frow) * 32 + fcol);
    __builtin_amdgcn_s_setprio(1);
    #pragma unroll
    for (int mi = 0; mi < FM; ++mi)
        #pragma unroll
        for (int ni = 0; ni < FN; ++ni)
            acc[mi][ni] = __builtin_amdgcn_mfma_f32_16x16x32_bf16(
                af[mi], bf[ni], acc[mi][ni], 0, 0, 0);
    __builtin_amdgcn_s_setprio(0);
}

// MODE 0: H1 = bf16(gelu(acc + bias[n]))                       (patch layer 1)
// MODE 1: out[(b*SEQ+NCLS+p)*D_+n] = acc + bias[n]             (patch layer 2)
// MODE 2: if src[m]==atom: HID = bf16(gelu(acc + bias[atom*H_+n]))  (cls in)
// MODE 3: if dst[m]==atom: out[(b*SEQ+nn)*D_+n] = (acc + bias[atom*D_+n])*wgt[m]
template <int MODE>
__global__ __launch_bounds__(256, 2)
void gemm_p2(const ushort_t* __restrict__ A,
             const ushort_t* __restrict__ Bm,
             int N, int K, int grid_n,
             const float* __restrict__ bias,
             float* __restrict__ outF,
             ushort_t* __restrict__ outB,
             const int* __restrict__ selIdx,
             const float* __restrict__ wgt) {
    constexpr int BM = 128, BN = 128, NT = 256;
    constexpr int FM = 4, FN = 4;

    __shared__ __align__(16) ushort_t A0[BM * 32], A1[BM * 32], A2[BM * 32], A3[BM * 32];
    __shared__ __align__(16) ushort_t B0[BN * 32], B1[BN * 32], B2[BN * 32], B3[BN * 32];

    // bijective XCD-chunk swizzle (m204), tile_n fastest (A-panel L2 reuse)
    const int nwg = gridDim.x;
    int bid = blockIdx.x;
    int q = nwg >> 3, r = nwg & 7;
    int xcd = bid & 7, slot = bid >> 3;
    int wg = (xcd < r ? xcd * (q + 1) : r * (q + 1) + (xcd - r) * q) + slot;
    int tile_m = wg / grid_n;
    int tile_n = wg - tile_m * grid_n;
    const int atom = blockIdx.z;

    const ushort_t* Ab = A  + (size_t)tile_m * BM * K;
    const ushort_t* Bb = Bm + ((size_t)atom * N + (size_t)tile_n * BN) * K;

    const int tid  = threadIdx.x;
    const int lane = tid & 63;
    const int wave = tid >> 6;
    const int arow0 = (wave >> 1) * 64;
    const int brow0 = (wave & 1) * 64;

    f32x4 acc[FM][FN];
    #pragma unroll
    for (int i = 0; i < FM; i++)
        #pragma unroll
        for (int j = 0; j < FN; j++)
            acc[i][j] = (f32x4){0.f, 0.f, 0.f, 0.f};

    const int nkt = K >> 5;   // 24 (K=768) or 96 (K=3072); both % 4 == 0

#define STAGE_T(T, SA, SB) \
    stage32<BM, NT>(Ab, K, (T) << 5, SA, tid); \
    stage32<BN, NT>(Bb, K, (T) << 5, SB, tid);

    // prologue: tiles 0 and 1 in flight
    STAGE_T(0, A0, B0)
    STAGE_T(1, A1, B1)

#define STEP(T, SA, SB, CA, CB) \
    if ((T) + 2 < nkt) { \
        STAGE_T((T) + 2, SA, SB) \
        asm volatile("s_waitcnt vmcnt(8)" ::: "memory"); \
    } else if ((T) + 1 < nkt) { \
        asm volatile("s_waitcnt vmcnt(4)" ::: "memory"); \
    } else { \
        asm volatile("s_waitcnt vmcnt(0)" ::: "memory"); \
    } \
    __syncthreads(); \
    compute32<FM, FN>(CA, CB, arow0, brow0, lane, acc);

    for (int t = 0; t < nkt; t += 4) {
        STEP(t + 0, A2, B2, A0, B0)
        STEP(t + 1, A3, B3, A1, B1)
        STEP(t + 2, A0, B0, A2, B2)
        STEP(t + 3, A1, B1, A3, B3)
    }
#undef STEP
#undef STAGE_T

    // epilogue: C/D layout col = lane&15, row = (lane>>4)*4 + reg
    const int frow = lane & 15;
    const int fq   = lane >> 4;
    #pragma unroll
    for (int mi = 0; mi < FM; mi++) {
        #pragma unroll
        for (int ni = 0; ni < FN; ni++) {
            int n = tile_n * BN + brow0 + ni * 16 + frow;
            float bn;
            if constexpr (MODE == 2)      bn = bias[atom * H_ + n];
            else if constexpr (MODE == 3) bn = bias[atom * D_ + n];
            else                          bn = bias[n];
            #pragma unroll
            for (int rr = 0; rr < 4; rr++) {
                int m = tile_m * BM + arow0 + mi * 16 + fq * 4 + rr;
                float v = acc[mi][ni][rr];
                if constexpr (MODE == 0) {
                    outB[(size_t)m * N + n] = f2bf(gelu_fast(v + bn));
                } else if constexpr (MODE == 1) {
                    int b = m / P_, p = m - b * P_;
                    outF[(size_t)(b * SEQ + NCLS + p) * D_ + n] = v + bn;
                } else if constexpr (MODE == 2) {
                    if (selIdx[m] == atom)
                        outB[(size_t)m * N + n] = f2bf(gelu_fast(v + bn));
                } else { // MODE 3
                    if (selIdx[m] == atom) {
                        int b = m / NCLS, nn = m - b * NCLS;
                        outF[(size_t)(b * SEQ + nn) * D_ + n] = (v + bn) * wgt[m];
                    }
                }
            }
        }
    }
}

// ---------------------------------------------------------------------------
// Launch
// ---------------------------------------------------------------------------
extern "C" void kernel_launch(void* const* d_in, const int* in_sizes, int n_in,
                              void* d_out, int out_size, void* d_ws, size_t ws_size,
                              hipStream_t stream) {
    const float* x   = (const float*)d_in[0];
    const float* w1  = (const float*)d_in[1];
    const float* b1  = (const float*)d_in[2];
    const float* w2  = (const float*)d_in[3];
    const float* b2  = (const float*)d_in[4];
    const float* gd  = (const float*)d_in[5];
    const float* aiw = (const float*)d_in[6];
    const float* aib = (const float*)d_in[7];
    const float* aow = (const float*)d_in[8];
    const float* aob = (const float*)d_in[9];
    float* out = (float*)d_out;

    char* ws = (char*)d_ws;
    ushort_t* Xp   = (ushort_t*)ws; ws += (size_t)NPATCH * D_ * 2;
    ushort_t* W1b  = (ushort_t*)ws; ws += (size_t)H_ * D_ * 2;
    ushort_t* W2b  = (ushort_t*)ws; ws += (size_t)D_ * H_ * 2;
    ushort_t* H1   = (ushort_t*)ws; ws += (size_t)NPATCH * H_ * 2;
    ushort_t* CLSb = (ushort_t*)ws; ws += (size_t)NPAIR * D_ * 2;
    ushort_t* AIWb = (ushort_t*)ws; ws += (size_t)NATOMS * H_ * D_ * 2;
    ushort_t* AOWb = (ushort_t*)ws; ws += (size_t)NATOMS * D_ * H_ * 2;
    ushort_t* HID  = (ushort_t*)ws; ws += (size_t)NPAIR * H_ * 2;
    int*   SRC = (int*)ws;   ws += NPAIR * 4;
    int*   DST = (int*)ws;   ws += NPAIR * 4;
    float* WGT = (float*)ws; ws += NPAIR * 4;

    // conversions
    split_x_kernel<<<(B_ * SEQ * D_ / 4 + 255) / 256, 256, 0, stream>>>(x, Xp, CLSb);
    cvt4_kernel<<<(H_ * D_ / 4 + 255) / 256, 256, 0, stream>>>(w1, W1b, H_ * D_);
    cvt4_kernel<<<(D_ * H_ / 4 + 255) / 256, 256, 0, stream>>>(w2, W2b, D_ * H_);
    cvt4_kernel<<<(NATOMS * H_ * D_ / 4 + 255) / 256, 256, 0, stream>>>(aiw, AIWb, NATOMS * H_ * D_);
    cvt4_kernel<<<(NATOMS * D_ * H_ / 4 + 255) / 256, 256, 0, stream>>>(aow, AOWb, NATOMS * D_ * H_);
    gate_kernel<<<NPAIR, 64, 0, stream>>>(x, gd, SRC, DST, WGT);

    // patch MLP
    gemm_p2<0><<<dim3(NPATCH / 128 * (H_ / 128), 1, 1), 256, 0, stream>>>(
        Xp, W1b, H_, D_, H_ / 128, b1, nullptr, H1, nullptr, nullptr);
    gemm_p2<1><<<dim3(NPATCH / 128 * (D_ / 128), 1, 1), 256, 0, stream>>>(
        H1, W2b, D_, H_, D_ / 128, b2, out, nullptr, nullptr, nullptr);

    // cls path: dense all-atom GEMMs with masked epilogue scatter (M = 384 = 3x128)
    gemm_p2<2><<<dim3(NPAIR / 128 * (H_ / 128), 1, NATOMS), 256, 0, stream>>>(
        CLSb, AIWb, H_, D_, H_ / 128, aib, nullptr, HID, SRC, nullptr);
    gemm_p2<3><<<dim3(NPAIR / 128 * (D_ / 128), 1, NATOMS), 256, 0, stream>>>(
        HID, AOWb, D_, H_, D_ / 128, aob, out, nullptr, DST, WGT);
}

// Round 6
// 345.441 us; speedup vs baseline: 1.1422x; 1.1422x over previous
//
#include <hip/hip_runtime.h>
#include <hip/hip_bf16.h>
#include <stdint.h>

// ---------------------------------------------------------------------------
// Problem constants
// ---------------------------------------------------------------------------
#define NCLS   6
#define NATOMS 5
#define B_     64
#define P_     196
#define D_     768
#define H_     3072
#define SEQ    (NCLS + P_)        // 202
#define NPATCH (B_ * P_)          // 12544
#define NPAIR  (B_ * NCLS)        // 384

typedef unsigned short ushort_t;
typedef __attribute__((ext_vector_type(8))) short  bf16x8;
typedef __attribute__((ext_vector_type(4))) float  f32x4;

// ---------------------------------------------------------------------------
// Helpers
// ---------------------------------------------------------------------------
// fast tanh-form GELU (max abs err ~1e-3; threshold budget 3.98e-2)
__device__ __forceinline__ float gelu_fast(float x) {
    float x2 = x * x;
    float y  = x * (1.59576912f + 0.07135482f * x2);
    float e  = __expf(y);
    return x * e / (e + 1.0f);
}

__device__ __forceinline__ ushort_t f2bf(float f) {
    uint32_t u = __builtin_bit_cast(uint32_t, f);
    u = (u + 0x7fffu + ((u >> 16) & 1u)) >> 16;
    return (ushort_t)u;
}

__device__ __forceinline__ void gload16(const ushort_t* g, ushort_t* l) {
    __builtin_amdgcn_global_load_lds(
        (const __attribute__((address_space(1))) uint32_t*)g,
        (__attribute__((address_space(3))) uint32_t*)l,
        16, 0, 0);
}

// ---------------------------------------------------------------------------
// fp32 -> bf16 conversion kernels
// ---------------------------------------------------------------------------
__global__ void cvt4_kernel(const float* __restrict__ in, ushort_t* __restrict__ out, int n) {
    int i = (blockIdx.x * blockDim.x + threadIdx.x) * 4;
    if (i >= n) return;
    float4 v = *(const float4*)(in + i);
    ushort4 o;
    o.x = f2bf(v.x); o.y = f2bf(v.y); o.z = f2bf(v.z); o.w = f2bf(v.w);
    *(ushort4*)(out + i) = o;
}

__global__ void split_x_kernel(const float* __restrict__ x,
                               ushort_t* __restrict__ xp,
                               ushort_t* __restrict__ cls) {
    int i = (blockIdx.x * blockDim.x + threadIdx.x) * 4;
    const int total = B_ * SEQ * D_;
    if (i >= total) return;
    int row = i / D_;
    int col = i - row * D_;
    int b = row / SEQ, s = row - b * SEQ;
    float4 v = *(const float4*)(x + i);
    ushort4 o;
    o.x = f2bf(v.x); o.y = f2bf(v.y); o.z = f2bf(v.z); o.w = f2bf(v.w);
    if (s < NCLS) {
        *(ushort4*)(cls + (size_t)(b * NCLS + s) * D_ + col) = o;
    } else {
        *(ushort4*)(xp + (size_t)(b * P_ + (s - NCLS)) * D_ + col) = o;
    }
}

// ---------------------------------------------------------------------------
// Gate
// ---------------------------------------------------------------------------
__global__ void gate_kernel(const float* __restrict__ x, const float* __restrict__ gd,
                            int* __restrict__ src, int* __restrict__ dst,
                            float* __restrict__ wgt) {
    int r = blockIdx.x;
    int b = r / NCLS, n = r - b * NCLS;
    const float* xr = x + (size_t)(b * SEQ + n) * D_;
    const float* g  = gd + (size_t)n * D_;
    int lane = threadIdx.x;
    float s = 0.f;
    for (int k = lane; k < D_; k += 64) s += xr[k] * g[k];
    #pragma unroll
    for (int off = 32; off > 0; off >>= 1) s += __shfl_down(s, off, 64);
    if (lane == 0) {
        float logit = s;
        bool left = (logit >= 0.f);
        float p = 1.f / (1.f + expf(-logit));
        float w = left ? p : (1.f - p);
        const int LK[NCLS] = {3, 4, 8, 9, 13, 14};
        const int RK[NCLS] = {15, 20, 16, 21, 17, 22};
        int key = left ? LK[n] : RK[n];
        src[r] = key / NATOMS;
        dst[r] = key % NATOMS;
        wgt[r] = w;
    }
}

// ===========================================================================
// 8-phase pipelined GEMM (patch MLP): C[m,n] = sum_k A[m,k]*B[n,k], B is NxK.
// BM x 256 tile (BM = 256 or 128), 8 waves (2M x 4N), BK=64 as 2 K-halves of
// [rows x 32] bf16, double-buffered.  4 phases per K-tile, 16*FMH MFMA each.
// RACE FIX vs r5: every phase that consumes freshly-DMA'd LDS does
//   stage-issue -> counted VMW -> s_barrier("memory") -> ds_read -> lgkmcnt(0)
// so the vmcnt guarantee precedes the reads (cross-thread via the barrier).
// mh=1 re-reads (data guaranteed a phase earlier) issue at the tail of the
// previous phase into a second register set to keep read/MFMA overlap.
// vmcnt accounting (LA_=BM/128 loads per A-half, LB_=2 per B-half):
//   steady VMW(2*LA_+LB_)  [drains exactly this tile's (A,B) K-half],
//   last tile VMW(LA_+LB_) then VMW(0).
// LDS swizzle: 16B-slot ^= (row>>1)&3 -> 2-way-max bank aliasing on
// ds_read_b128 (free per m136); applied as inverse-swizzled GLOBAL source
// (linear gload_lds dest) + swizzled read address (rule #21).
// ===========================================================================

template <int ROWS>
__device__ __forceinline__ void stage_half(const ushort_t* __restrict__ gpanel, int K,
                                           int kbase, ushort_t* lhalf, int tid) {
    constexpr int LOADS = ROWS * 4 / 512;
    #pragma unroll
    for (int l = 0; l < LOADS; ++l) {
        int c = (l << 9) + tid;
        int row = c >> 2;
        int col = ((c & 3) ^ ((row >> 1) & 3)) << 3;
        gload16(gpanel + (size_t)row * K + kbase + col, lhalf + ((size_t)c << 3));
    }
}

#define BAR     asm volatile("s_barrier" ::: "memory")
#define VMW(N)  asm volatile("s_waitcnt vmcnt(" #N ")" ::: "memory")
#define VMW_STEADY do { if constexpr (BM == 256) VMW(6); else VMW(4); } while (0)
#define VMW_LAST1  do { if constexpr (BM == 256) VMW(4); else VMW(3); } while (0)

#define READ_A(DST, BUF, KS, MH) { \
    const ushort_t* sa_ = &LA[BUF][KS][abase + (MH) * (BM * 8)]; \
    _Pragma("unroll") \
    for (int q_ = 0; q_ < FMH; ++q_) DST[q_] = *(const bf16x8*)(sa_ + q_ * 512); }

#define READ_B(BUF, KS) { \
    const ushort_t* sb_ = &LB[BUF][KS][bbase]; \
    _Pragma("unroll") \
    for (int q_ = 0; q_ < 4; ++q_) bf[q_] = *(const bf16x8*)(sb_ + q_ * 512); }

#define MFMA_Q(SRC, MH) \
    asm volatile("s_waitcnt lgkmcnt(0)" ::: "memory"); \
    __builtin_amdgcn_sched_barrier(0); \
    __builtin_amdgcn_s_setprio(1); \
    _Pragma("unroll") \
    for (int mi_ = 0; mi_ < FMH; ++mi_) { \
        _Pragma("unroll") \
        for (int ni_ = 0; ni_ < 4; ++ni_) \
            acc[(MH) * FMH + mi_][ni_] = __builtin_amdgcn_mfma_f32_16x16x32_bf16( \
                SRC[mi_], bf[ni_], acc[(MH) * FMH + mi_][ni_], 0, 0, 0); \
    } \
    __builtin_amdgcn_s_setprio(0); \
    __builtin_amdgcn_sched_barrier(0);

// steady-state K-tile: compute BUF, stage K-tile KT1 into SBUF
#define KTILE_STAGE(BUF, SBUF, KT1) { \
    const int kb_ = (KT1) << 6; \
    stage_half<BM>(Ab, K, kb_, &LA[SBUF][0][0], tid); \
    VMW_STEADY; BAR; \
    READ_A(af, BUF, 0, 0) READ_B(BUF, 0) \
    MFMA_Q(af, 0) \
    READ_A(af2, BUF, 0, 1) \
    BAR; \
    stage_half<256>(Bb, K, kb_, &LB[SBUF][0][0], tid); \
    BAR; \
    MFMA_Q(af2, 1) \
    BAR; \
    stage_half<BM>(Ab, K, kb_ + 32, &LA[SBUF][1][0], tid); \
    VMW_STEADY; BAR; \
    READ_A(af, BUF, 1, 0) READ_B(BUF, 1) \
    MFMA_Q(af, 0) \
    READ_A(af2, BUF, 1, 1) \
    BAR; \
    stage_half<256>(Bb, K, kb_ + 32, &LB[SBUF][1][0], tid); \
    BAR; \
    MFMA_Q(af2, 1) \
    BAR; }

// final K-tile: no staging; drain (LA_+LB_) then 0
#define KTILE_LAST(BUF) { \
    VMW_LAST1; BAR; \
    READ_A(af, BUF, 0, 0) READ_B(BUF, 0) \
    MFMA_Q(af, 0) \
    READ_A(af2, BUF, 0, 1) \
    MFMA_Q(af2, 1) \
    VMW(0); BAR; \
    READ_A(af, BUF, 1, 0) READ_B(BUF, 1) \
    MFMA_Q(af, 0) \
    READ_A(af2, BUF, 1, 1) \
    MFMA_Q(af2, 1) }

// MODE 0: H1 = bf16(gelu(acc + bias[n]))          (patch layer 1)
// MODE 1: out[(b*SEQ+NCLS+p)*D_+n] = acc+bias[n]  (patch layer 2)
template <int MODE, int BM>
__global__ __launch_bounds__(512, 2)
void gemm8p(const ushort_t* __restrict__ A, const ushort_t* __restrict__ Bm,
            int N, int K, int grid_n,
            const float* __restrict__ bias,
            float* __restrict__ outF, ushort_t* __restrict__ outB) {
    constexpr int FMH = BM / 64;   // A-frags per MFMA quadrant (4 or 2)

    __shared__ __align__(16) ushort_t LA[2][2][BM * 32];
    __shared__ __align__(16) ushort_t LB[2][2][8192];

    // bijective XCD-chunk swizzle (m204), tile_n fastest (A-panel L2 reuse)
    const int nwg = gridDim.x;
    int bid = blockIdx.x;
    int q = nwg >> 3, r = nwg & 7;
    int xcd = bid & 7, slot = bid >> 3;
    int wg = (xcd < r ? xcd * (q + 1) : r * (q + 1) + (xcd - r) * q) + slot;
    int tile_m = wg / grid_n;
    int tile_n = wg - tile_m * grid_n;

    const ushort_t* Ab = A  + (size_t)tile_m * BM * K;
    const ushort_t* Bb = Bm + (size_t)tile_n * 256 * K;

    const int tid  = threadIdx.x;
    const int lane = tid & 63;
    const int wave = tid >> 6;
    const int wr = wave >> 2;   // 0..1 : A rows [wr*BM/2, +BM/2)
    const int wc = wave & 3;    // 0..3 : B rows [wc*64, +64)

    const int frow = lane & 15;
    const int fsl  = lane >> 4; // 16B-slot (k-offset) within 32-col half
    // swizzled per-thread fragment base (elements within a [rows][32] half)
    const int rbase = frow * 32 + ((fsl ^ ((frow >> 1) & 3)) << 3);
    const int abase = wr * (BM * 16) + rbase;   // + mh*(BM*8) + mi*512
    const int bbase = wc * 2048 + rbase;        // + ni*512

    f32x4 acc[2 * FMH][4];
    #pragma unroll
    for (int i = 0; i < 2 * FMH; i++)
        #pragma unroll
        for (int j = 0; j < 4; j++)
            acc[i][j] = (f32x4){0.f, 0.f, 0.f, 0.f};

    const int nkt = K >> 6;   // 12 (K=768) or 48 (K=3072): even, >= 2

    // prologue: tile 0 -> buf 0; queue order (A0,B0,A1,B1) matches accounting
    stage_half<BM >(Ab, K, 0,  &LA[0][0][0], tid);
    stage_half<256>(Bb, K, 0,  &LB[0][0][0], tid);
    stage_half<BM >(Ab, K, 32, &LA[0][1][0], tid);
    stage_half<256>(Bb, K, 32, &LB[0][1][0], tid);

    bf16x8 af[FMH], af2[FMH], bf[4];

    for (int tb = 0; tb + 2 < nkt; tb += 2) {
        KTILE_STAGE(0, 1, tb + 1)
        KTILE_STAGE(1, 0, tb + 2)
    }
    KTILE_STAGE(0, 1, nkt - 1)
    KTILE_LAST(1)

    // epilogue: C/D layout col = lane&15, row = (lane>>4)*4 + reg
    const int fq = lane >> 4;
    #pragma unroll
    for (int mi = 0; mi < 2 * FMH; mi++) {
        #pragma unroll
        for (int ni = 0; ni < 4; ni++) {
            int n = tile_n * 256 + wc * 64 + ni * 16 + frow;
            float bn = bias[n];
            #pragma unroll
            for (int rr = 0; rr < 4; rr++) {
                int m = tile_m * BM + wr * (BM / 2) + mi * 16 + fq * 4 + rr;
                float v = acc[mi][ni][rr];
                if constexpr (MODE == 0) {
                    outB[(size_t)m * N + n] = f2bf(gelu_fast(v + bn));
                } else {
                    int b = m / P_, p = m - b * P_;
                    outF[(size_t)(b * SEQ + NCLS + p) * D_ + n] = v + bn;
                }
            }
        }
    }
}

// ---------------------------------------------------------------------------
// cls-path GEMM: round-3 2-phase double-buffered structure (proven), BK=64.
// ---------------------------------------------------------------------------
template <int ROWS, int NT>
__device__ __forceinline__ void stage64(const ushort_t* __restrict__ gbase, int K,
                                        int k0, ushort_t* lds, int tid) {
    constexpr int LOADS = ROWS * 64 * 2 / (NT * 16);
    #pragma unroll
    for (int l = 0; l < LOADS; ++l) {
        int c = l * NT + tid;
        gload16(gbase + (size_t)(c >> 3) * K + k0 + ((c & 7) << 3),
                lds + (size_t)c * 8);
    }
}

template <int FM, int FN>
__device__ __forceinline__ void compute64(const ushort_t* sA, const ushort_t* sB,
                                          int arow0, int brow0, int lane,
                                          f32x4 (&acc)[FM][FN]) {
    const int frow = lane & 15;
    const int fcol = (lane >> 4) * 8;
    #pragma unroll
    for (int ks = 0; ks < 2; ++ks) {
        bf16x8 af[FM], bfv[FN];
        #pragma unroll
        for (int mi = 0; mi < FM; ++mi)
            af[mi] = *(const bf16x8*)(sA + (size_t)(arow0 + mi * 16 + frow) * 64 + ks * 32 + fcol);
        #pragma unroll
        for (int ni = 0; ni < FN; ++ni)
            bfv[ni] = *(const bf16x8*)(sB + (size_t)(brow0 + ni * 16 + frow) * 64 + ks * 32 + fcol);
        #pragma unroll
        for (int mi = 0; mi < FM; ++mi)
            #pragma unroll
            for (int ni = 0; ni < FN; ++ni)
                acc[mi][ni] = __builtin_amdgcn_mfma_f32_16x16x32_bf16(
                    af[mi], bfv[ni], acc[mi][ni], 0, 0, 0);
    }
}

// MODE 2: if src[m]==atom: HID = bf16(gelu(acc + bias[atom*H_+n]))
// MODE 3: if dst[m]==atom: out[(b*SEQ+nn)*D_+n] = (acc + bias[atom*D_+n])*wgt[m]
template <int MODE, int BMc, int BNc, int WM, int WN>
__global__ __launch_bounds__(WM * WN * 64, 2)
void gemm2p(const ushort_t* __restrict__ A,
            const ushort_t* __restrict__ Bm,
            int N, int K, int grid_n,
            const float* __restrict__ bias,
            float* __restrict__ outF,
            ushort_t* __restrict__ outB,
            const int* __restrict__ selIdx,
            const float* __restrict__ wgt) {
    constexpr int NT = WM * WN * 64;
    constexpr int FM = BMc / WM / 16;
    constexpr int FN = BNc / WN / 16;

    __shared__ __align__(16) ushort_t A0[BMc * 64], A1[BMc * 64];
    __shared__ __align__(16) ushort_t B0[BNc * 64], B1[BNc * 64];

    const int nwg = gridDim.x;
    int bid = blockIdx.x;
    int q = nwg >> 3, r = nwg & 7;
    int xcd = bid & 7, slot = bid >> 3;
    int wg = (xcd < r ? xcd * (q + 1) : r * (q + 1) + (xcd - r) * q) + slot;
    int tile_m = wg / grid_n;
    int tile_n = wg - tile_m * grid_n;
    const int atom = blockIdx.z;

    const ushort_t* Ab = A  + (size_t)tile_m * BMc * K;
    const ushort_t* Bb = Bm + ((size_t)atom * N + (size_t)tile_n * BNc) * K;

    const int tid  = threadIdx.x;
    const int lane = tid & 63;
    const int wave = tid >> 6;
    const int arow0 = (wave / WN) * (BMc / WM);
    const int brow0 = (wave % WN) * (BNc / WN);

    f32x4 acc[FM][FN];
    #pragma unroll
    for (int i = 0; i < FM; i++)
        #pragma unroll
        for (int j = 0; j < FN; j++)
            acc[i][j] = (f32x4){0.f, 0.f, 0.f, 0.f};

    const int nkt = K >> 6;

    stage64<BMc, NT>(Ab, K, 0, A0, tid);
    stage64<BNc, NT>(Bb, K, 0, B0, tid);
    asm volatile("s_waitcnt vmcnt(0)" ::: "memory");
    __syncthreads();

    for (int t = 0; t < nkt; t += 2) {
        stage64<BMc, NT>(Ab, K, (t + 1) << 6, A1, tid);
        stage64<BNc, NT>(Bb, K, (t + 1) << 6, B1, tid);
        compute64<FM, FN>(A0, B0, arow0, brow0, lane, acc);
        asm volatile("s_waitcnt vmcnt(0)" ::: "memory");
        __syncthreads();
        if (t + 2 < nkt) {
            stage64<BMc, NT>(Ab, K, (t + 2) << 6, A0, tid);
            stage64<BNc, NT>(Bb, K, (t + 2) << 6, B0, tid);
        }
        compute64<FM, FN>(A1, B1, arow0, brow0, lane, acc);
        asm volatile("s_waitcnt vmcnt(0)" ::: "memory");
        __syncthreads();
    }

    const int frow = lane & 15;
    const int fq   = lane >> 4;
    #pragma unroll
    for (int mi = 0; mi < FM; mi++) {
        #pragma unroll
        for (int ni = 0; ni < FN; ni++) {
            int n = tile_n * BNc + brow0 + ni * 16 + frow;
            float bn;
            if constexpr (MODE == 2) bn = bias[atom * H_ + n];
            else                     bn = bias[atom * D_ + n];
            #pragma unroll
            for (int rr = 0; rr < 4; rr++) {
                int m = tile_m * BMc + arow0 + mi * 16 + fq * 4 + rr;
                float v = acc[mi][ni][rr];
                if constexpr (MODE == 2) {
                    if (selIdx[m] == atom)
                        outB[(size_t)m * N + n] = f2bf(gelu_fast(v + bn));
                } else { // MODE 3
                    if (selIdx[m] == atom) {
                        int b = m / NCLS, nn = m - b * NCLS;
                        outF[(size_t)(b * SEQ + nn) * D_ + n] = (v + bn) * wgt[m];
                    }
                }
            }
        }
    }
}

// ---------------------------------------------------------------------------
// Launch
// ---------------------------------------------------------------------------
extern "C" void kernel_launch(void* const* d_in, const int* in_sizes, int n_in,
                              void* d_out, int out_size, void* d_ws, size_t ws_size,
                              hipStream_t stream) {
    const float* x   = (const float*)d_in[0];
    const float* w1  = (const float*)d_in[1];
    const float* b1  = (const float*)d_in[2];
    const float* w2  = (const float*)d_in[3];
    const float* b2  = (const float*)d_in[4];
    const float* gd  = (const float*)d_in[5];
    const float* aiw = (const float*)d_in[6];
    const float* aib = (const float*)d_in[7];
    const float* aow = (const float*)d_in[8];
    const float* aob = (const float*)d_in[9];
    float* out = (float*)d_out;

    char* ws = (char*)d_ws;
    ushort_t* Xp   = (ushort_t*)ws; ws += (size_t)NPATCH * D_ * 2;
    ushort_t* W1b  = (ushort_t*)ws; ws += (size_t)H_ * D_ * 2;
    ushort_t* W2b  = (ushort_t*)ws; ws += (size_t)D_ * H_ * 2;
    ushort_t* H1   = (ushort_t*)ws; ws += (size_t)NPATCH * H_ * 2;
    ushort_t* CLSb = (ushort_t*)ws; ws += (size_t)NPAIR * D_ * 2;
    ushort_t* AIWb = (ushort_t*)ws; ws += (size_t)NATOMS * H_ * D_ * 2;
    ushort_t* AOWb = (ushort_t*)ws; ws += (size_t)NATOMS * D_ * H_ * 2;
    ushort_t* HID  = (ushort_t*)ws; ws += (size_t)NPAIR * H_ * 2;
    int*   SRC = (int*)ws;   ws += NPAIR * 4;
    int*   DST = (int*)ws;   ws += NPAIR * 4;
    float* WGT = (float*)ws; ws += NPAIR * 4;

    // conversions
    split_x_kernel<<<(B_ * SEQ * D_ / 4 + 255) / 256, 256, 0, stream>>>(x, Xp, CLSb);
    cvt4_kernel<<<(H_ * D_ / 4 + 255) / 256, 256, 0, stream>>>(w1, W1b, H_ * D_);
    cvt4_kernel<<<(D_ * H_ / 4 + 255) / 256, 256, 0, stream>>>(w2, W2b, D_ * H_);
    cvt4_kernel<<<(NATOMS * H_ * D_ / 4 + 255) / 256, 256, 0, stream>>>(aiw, AIWb, NATOMS * H_ * D_);
    cvt4_kernel<<<(NATOMS * D_ * H_ / 4 + 255) / 256, 256, 0, stream>>>(aow, AOWb, NATOMS * D_ * H_);
    gate_kernel<<<NPAIR, 64, 0, stream>>>(x, gd, SRC, DST, WGT);

    // patch MLP: 8-phase kernels.  GEMM0: 256x256 (588 blocks).
    // GEMM1: 128x256 (294 blocks — fixes the 147-block underfill at 256^2).
    gemm8p<0, 256><<<dim3(NPATCH / 256 * (H_ / 256), 1, 1), 512, 0, stream>>>(
        Xp, W1b, H_, D_, H_ / 256, b1, nullptr, H1);
    gemm8p<1, 128><<<dim3(NPATCH / 128 * (D_ / 256), 1, 1), 512, 0, stream>>>(
        H1, W2b, D_, H_, D_ / 256, b2, out, nullptr);

    // cls path: dense all-atom GEMMs with masked epilogue scatter (round-3 proven)
    gemm2p<2, 64, 128, 1, 2><<<dim3(NPAIR / 64 * (H_ / 128), 1, NATOMS), 128, 0, stream>>>(
        CLSb, AIWb, H_, D_, H_ / 128, aib, nullptr, HID, SRC, nullptr);
    gemm2p<3, 64, 128, 1, 2><<<dim3(NPAIR / 64 * (D_ / 128), 1, NATOMS), 128, 0, stream>>>(
        HID, AOWb, D_, H_, D_ / 128, aob, out, nullptr, DST, WGT);
}

// Round 7
// 342.784 us; speedup vs baseline: 1.1510x; 1.0078x over previous
//
#include <hip/hip_runtime.h>
#include <hip/hip_bf16.h>
#include <stdint.h>

// ---------------------------------------------------------------------------
// Problem constants
// ---------------------------------------------------------------------------
#define NCLS   6
#define NATOMS 5
#define B_     64
#define P_     196
#define D_     768
#define H_     3072
#define SEQ    (NCLS + P_)        // 202
#define NPATCH (B_ * P_)          // 12544
#define NPAIR  (B_ * NCLS)        // 384

typedef unsigned short ushort_t;
typedef __attribute__((ext_vector_type(8))) short  bf16x8;
typedef __attribute__((ext_vector_type(4))) float  f32x4;

// ---------------------------------------------------------------------------
// Helpers
// ---------------------------------------------------------------------------
// fast tanh-form GELU (max abs err ~1e-3; threshold budget 3.98e-2)
__device__ __forceinline__ float gelu_fast(float x) {
    float x2 = x * x;
    float y  = x * (1.59576912f + 0.07135482f * x2);
    float e  = __expf(y);
    return x * e / (e + 1.0f);
}

__device__ __forceinline__ ushort_t f2bf(float f) {
    uint32_t u = __builtin_bit_cast(uint32_t, f);
    u = (u + 0x7fffu + ((u >> 16) & 1u)) >> 16;
    return (ushort_t)u;
}

__device__ __forceinline__ void gload16(const ushort_t* g, ushort_t* l) {
    __builtin_amdgcn_global_load_lds(
        (const __attribute__((address_space(1))) uint32_t*)g,
        (__attribute__((address_space(3))) uint32_t*)l,
        16, 0, 0);
}

// ---------------------------------------------------------------------------
// fp32 -> bf16 conversion kernels
// ---------------------------------------------------------------------------
__global__ void cvt4_kernel(const float* __restrict__ in, ushort_t* __restrict__ out, int n) {
    int i = (blockIdx.x * blockDim.x + threadIdx.x) * 4;
    if (i >= n) return;
    float4 v = *(const float4*)(in + i);
    ushort4 o;
    o.x = f2bf(v.x); o.y = f2bf(v.y); o.z = f2bf(v.z); o.w = f2bf(v.w);
    *(ushort4*)(out + i) = o;
}

__global__ void split_x_kernel(const float* __restrict__ x,
                               ushort_t* __restrict__ xp,
                               ushort_t* __restrict__ cls) {
    int i = (blockIdx.x * blockDim.x + threadIdx.x) * 4;
    const int total = B_ * SEQ * D_;
    if (i >= total) return;
    int row = i / D_;
    int col = i - row * D_;
    int b = row / SEQ, s = row - b * SEQ;
    float4 v = *(const float4*)(x + i);
    ushort4 o;
    o.x = f2bf(v.x); o.y = f2bf(v.y); o.z = f2bf(v.z); o.w = f2bf(v.w);
    if (s < NCLS) {
        *(ushort4*)(cls + (size_t)(b * NCLS + s) * D_ + col) = o;
    } else {
        *(ushort4*)(xp + (size_t)(b * P_ + (s - NCLS)) * D_ + col) = o;
    }
}

// ---------------------------------------------------------------------------
// Gate
// ---------------------------------------------------------------------------
__global__ void gate_kernel(const float* __restrict__ x, const float* __restrict__ gd,
                            int* __restrict__ src, int* __restrict__ dst,
                            float* __restrict__ wgt) {
    int r = blockIdx.x;
    int b = r / NCLS, n = r - b * NCLS;
    const float* xr = x + (size_t)(b * SEQ + n) * D_;
    const float* g  = gd + (size_t)n * D_;
    int lane = threadIdx.x;
    float s = 0.f;
    for (int k = lane; k < D_; k += 64) s += xr[k] * g[k];
    #pragma unroll
    for (int off = 32; off > 0; off >>= 1) s += __shfl_down(s, off, 64);
    if (lane == 0) {
        float logit = s;
        bool left = (logit >= 0.f);
        float p = 1.f / (1.f + expf(-logit));
        float w = left ? p : (1.f - p);
        const int LK[NCLS] = {3, 4, 8, 9, 13, 14};
        const int RK[NCLS] = {15, 20, 16, 21, 17, 22};
        int key = left ? LK[n] : RK[n];
        src[r] = key / NATOMS;
        dst[r] = key % NATOMS;
        wgt[r] = w;
    }
}

// ===========================================================================
// Read-ahead 4-phase pipelined GEMM (patch MLP): C = A * B^T, B in NxK.
// BM x 256 tile, 8 waves (2M x 4N), BK=64 as 2 K-halves of [rows x 32] bf16,
// double-buffered (2 dbuf x 2 half per tensor).
//
// SCHEDULE (fix vs r6's exposed-latency phases): each phase issues the NEXT
// phase's fragment ds_reads into a ping-pong register set (aR0/aR1, bR0/bR1),
// then runs its MFMA cluster on registers read one phase earlier (compiler
// emits the counted lgkmcnt; operands are already resident -> ~0 stall).
// Phase p layout:  BAR ; [reads for p+1] ; setprio1 MFMA setprio0 ; stage ;
// [counted VMW at P0/P2 tails].
//
// Per-wave vmcnt ledger (stage = 2 loads at BM=256; A=1/B=2 at BM=128):
//   P0 tail: in flight {A[cb][1], B[cb][1], A[nb][0]} -> VMW(2)/(1) drains
//            the two halves P1's reads target (A,B of this tile's h1).
//   P2 tail: in flight {A[nb][0], B[nb][0], A[nb][1]} -> VMW(2)/(1) drains
//            next tile's h0 (targeted by P3's read-ahead for next P0).
//   Prologue VMW(4)/(3); last tile P0 tail VMW(0). Never 0 mid-loop.
// Read-ahead map: P0 issues A[cb][0]mh1; P1: A[cb][1]mh0 + B[cb][1];
//                 P2: A[cb][1]mh1;      P3: A[nb][0]mh0 + B[nb][0].
// (B regs are reused across the two phases of a K-half.)
//
// LDS swizzle (proven r6, 0 bank conflicts): 16B-slot ^= (row>>1)&3,
// inverse-swizzled GLOBAL source + swizzled read address (rule #21).
// ===========================================================================

template <int ROWS>
__device__ __forceinline__ void stage_half(const ushort_t* __restrict__ gpanel, int K,
                                           int kbase, ushort_t* lhalf, int tid) {
    constexpr int LOADS = ROWS * 4 / 512;
    #pragma unroll
    for (int l = 0; l < LOADS; ++l) {
        int c = (l << 9) + tid;
        int row = c >> 2;
        int col = ((c & 3) ^ ((row >> 1) & 3)) << 3;
        gload16(gpanel + (size_t)row * K + kbase + col, lhalf + ((size_t)c << 3));
    }
}

#define BAR     asm volatile("s_barrier" ::: "memory")
#define VMW(N)  asm volatile("s_waitcnt vmcnt(" #N ")" ::: "memory")
#define VMWA    do { if constexpr (BM == 256) { VMW(2); } else { VMW(1); } } while (0)

#define READ_A(DST, BUF, KS, MH) { \
    const ushort_t* sa_ = &LA[BUF][KS][abase + (MH) * (BM * 8)]; \
    _Pragma("unroll") \
    for (int q_ = 0; q_ < FMH; ++q_) DST[q_] = *(const bf16x8*)(sa_ + q_ * 512); }

#define READ_B(DST, BUF, KS) { \
    const ushort_t* sb_ = &LB[BUF][KS][bbase]; \
    _Pragma("unroll") \
    for (int q_ = 0; q_ < 4; ++q_) DST[q_] = *(const bf16x8*)(sb_ + q_ * 512); }

#define MFMA_Q(ASET, BSET, MH) do { \
    __builtin_amdgcn_s_setprio(1); \
    _Pragma("unroll") \
    for (int mi_ = 0; mi_ < FMH; ++mi_) { \
        _Pragma("unroll") \
        for (int ni_ = 0; ni_ < 4; ++ni_) \
            acc[(MH) * FMH + mi_][ni_] = __builtin_amdgcn_mfma_f32_16x16x32_bf16( \
                ASET[mi_], BSET[ni_], acc[(MH) * FMH + mi_][ni_], 0, 0, 0); \
    } \
    __builtin_amdgcn_s_setprio(0); \
    __builtin_amdgcn_sched_barrier(0); \
} while (0)

// steady K-tile: compute buf CB, stage K-tile at byte-col KB into buf NB
#define KT_STEADY(CB, NB, KB) \
    BAR; READ_A(aR1, CB, 0, 1) MFMA_Q(aR0, bR0, 0); \
    stage_half<BM>(Ab, K, KB, &LA[NB][0][0], tid); VMWA; \
    BAR; READ_A(aR0, CB, 1, 0) READ_B(bR1, CB, 1) MFMA_Q(aR1, bR0, 1); \
    stage_half<256>(Bb, K, KB, &LB[NB][0][0], tid); \
    BAR; READ_A(aR1, CB, 1, 1) MFMA_Q(aR0, bR1, 0); \
    stage_half<BM>(Ab, K, (KB) + 32, &LA[NB][1][0], tid); VMWA; \
    BAR; READ_A(aR0, NB, 0, 0) READ_B(bR0, NB, 0) MFMA_Q(aR1, bR1, 1); \
    stage_half<256>(Bb, K, (KB) + 32, &LB[NB][1][0], tid);

// MODE 0: H1 = bf16(gelu(acc + bias[n]))          (patch layer 1)
// MODE 1: out[(b*SEQ+NCLS+p)*D_+n] = acc+bias[n]  (patch layer 2)
template <int MODE, int BM>
__global__ __launch_bounds__(512, 2)
void gemm8p(const ushort_t* __restrict__ A, const ushort_t* __restrict__ Bm,
            int N, int K, int grid_n,
            const float* __restrict__ bias,
            float* __restrict__ outF, ushort_t* __restrict__ outB) {
    constexpr int FMH = BM / 64;   // A-frags per MFMA quadrant (4 or 2)

    __shared__ __align__(16) ushort_t LA[2][2][BM * 32];
    __shared__ __align__(16) ushort_t LB[2][2][8192];

    // bijective XCD-chunk swizzle (m204), tile_n fastest (A-panel L2 reuse)
    const int nwg = gridDim.x;
    int bid = blockIdx.x;
    int q = nwg >> 3, r = nwg & 7;
    int xcd = bid & 7, slot = bid >> 3;
    int wg = (xcd < r ? xcd * (q + 1) : r * (q + 1) + (xcd - r) * q) + slot;
    int tile_m = wg / grid_n;
    int tile_n = wg - tile_m * grid_n;

    const ushort_t* Ab = A  + (size_t)tile_m * BM * K;
    const ushort_t* Bb = Bm + (size_t)tile_n * 256 * K;

    const int tid  = threadIdx.x;
    const int lane = tid & 63;
    const int wave = tid >> 6;
    const int wr = wave >> 2;   // 0..1 : A rows [wr*BM/2, +BM/2)
    const int wc = wave & 3;    // 0..3 : B rows [wc*64, +64)

    const int frow = lane & 15;
    const int fsl  = lane >> 4; // 16B-slot (k-offset) within 32-col half
    const int rbase = frow * 32 + ((fsl ^ ((frow >> 1) & 3)) << 3);
    const int abase = wr * (BM * 16) + rbase;   // + mh*(BM*8) + mi*512
    const int bbase = wc * 2048 + rbase;        // + ni*512

    f32x4 acc[2 * FMH][4];
    #pragma unroll
    for (int i = 0; i < 2 * FMH; i++)
        #pragma unroll
        for (int j = 0; j < 4; j++)
            acc[i][j] = (f32x4){0.f, 0.f, 0.f, 0.f};

    const int nkt = K >> 6;   // 12 (K=768) or 48 (K=3072): even, >= 4

    bf16x8 aR0[FMH], aR1[FMH], bR0[4], bR1[4];

    // prologue: stage tile 0 -> buf 0 (order A0,B0,A1,B1 drives the ledger)
    stage_half<BM >(Ab, K, 0,  &LA[0][0][0], tid);
    stage_half<256>(Bb, K, 0,  &LB[0][0][0], tid);
    stage_half<BM >(Ab, K, 32, &LA[0][1][0], tid);
    stage_half<256>(Bb, K, 32, &LB[0][1][0], tid);
    if constexpr (BM == 256) { VMW(4); } else { VMW(3); }
    BAR;
    READ_A(aR0, 0, 0, 0)
    READ_B(bR0, 0, 0)

    for (int t = 0; t + 2 < nkt; t += 2) {
        KT_STEADY(0, 1, (t + 1) << 6)
        KT_STEADY(1, 0, (t + 2) << 6)
    }
    KT_STEADY(0, 1, (nkt - 1) << 6)
    // last K-tile (buf 1): no staging; drain remaining halves at P0
    BAR; READ_A(aR1, 1, 0, 1) MFMA_Q(aR0, bR0, 0); VMW(0);
    BAR; READ_A(aR0, 1, 1, 0) READ_B(bR1, 1, 1) MFMA_Q(aR1, bR0, 1);
    BAR; READ_A(aR1, 1, 1, 1) MFMA_Q(aR0, bR1, 0);
    MFMA_Q(aR1, bR1, 1);

    // epilogue: C/D layout col = lane&15, row = (lane>>4)*4 + reg
    const int fq = lane >> 4;
    #pragma unroll
    for (int mi = 0; mi < 2 * FMH; mi++) {
        #pragma unroll
        for (int ni = 0; ni < 4; ni++) {
            int n = tile_n * 256 + wc * 64 + ni * 16 + frow;
            float bn = bias[n];
            #pragma unroll
            for (int rr = 0; rr < 4; rr++) {
                int m = tile_m * BM + wr * (BM / 2) + mi * 16 + fq * 4 + rr;
                float v = acc[mi][ni][rr];
                if constexpr (MODE == 0) {
                    outB[(size_t)m * N + n] = f2bf(gelu_fast(v + bn));
                } else {
                    int b = m / P_, p = m - b * P_;
                    outF[(size_t)(b * SEQ + NCLS + p) * D_ + n] = v + bn;
                }
            }
        }
    }
}

// ---------------------------------------------------------------------------
// cls-path GEMM: round-3 2-phase double-buffered structure (proven), BK=64.
// ---------------------------------------------------------------------------
template <int ROWS, int NT>
__device__ __forceinline__ void stage64(const ushort_t* __restrict__ gbase, int K,
                                        int k0, ushort_t* lds, int tid) {
    constexpr int LOADS = ROWS * 64 * 2 / (NT * 16);
    #pragma unroll
    for (int l = 0; l < LOADS; ++l) {
        int c = l * NT + tid;
        gload16(gbase + (size_t)(c >> 3) * K + k0 + ((c & 7) << 3),
                lds + (size_t)c * 8);
    }
}

template <int FM, int FN>
__device__ __forceinline__ void compute64(const ushort_t* sA, const ushort_t* sB,
                                          int arow0, int brow0, int lane,
                                          f32x4 (&acc)[FM][FN]) {
    const int frow = lane & 15;
    const int fcol = (lane >> 4) * 8;
    #pragma unroll
    for (int ks = 0; ks < 2; ++ks) {
        bf16x8 af[FM], bfv[FN];
        #pragma unroll
        for (int mi = 0; mi < FM; ++mi)
            af[mi] = *(const bf16x8*)(sA + (size_t)(arow0 + mi * 16 + frow) * 64 + ks * 32 + fcol);
        #pragma unroll
        for (int ni = 0; ni < FN; ++ni)
            bfv[ni] = *(const bf16x8*)(sB + (size_t)(brow0 + ni * 16 + frow) * 64 + ks * 32 + fcol);
        #pragma unroll
        for (int mi = 0; mi < FM; ++mi)
            #pragma unroll
            for (int ni = 0; ni < FN; ++ni)
                acc[mi][ni] = __builtin_amdgcn_mfma_f32_16x16x32_bf16(
                    af[mi], bfv[ni], acc[mi][ni], 0, 0, 0);
    }
}

// MODE 2: if src[m]==atom: HID = bf16(gelu(acc + bias[atom*H_+n]))
// MODE 3: if dst[m]==atom: out[(b*SEQ+nn)*D_+n] = (acc + bias[atom*D_+n])*wgt[m]
template <int MODE, int BMc, int BNc, int WM, int WN>
__global__ __launch_bounds__(WM * WN * 64, 2)
void gemm2p(const ushort_t* __restrict__ A,
            const ushort_t* __restrict__ Bm,
            int N, int K, int grid_n,
            const float* __restrict__ bias,
            float* __restrict__ outF,
            ushort_t* __restrict__ outB,
            const int* __restrict__ selIdx,
            const float* __restrict__ wgt) {
    constexpr int NT = WM * WN * 64;
    constexpr int FM = BMc / WM / 16;
    constexpr int FN = BNc / WN / 16;

    __shared__ __align__(16) ushort_t A0[BMc * 64], A1[BMc * 64];
    __shared__ __align__(16) ushort_t B0[BNc * 64], B1[BNc * 64];

    const int nwg = gridDim.x;
    int bid = blockIdx.x;
    int q = nwg >> 3, r = nwg & 7;
    int xcd = bid & 7, slot = bid >> 3;
    int wg = (xcd < r ? xcd * (q + 1) : r * (q + 1) + (xcd - r) * q) + slot;
    int tile_m = wg / grid_n;
    int tile_n = wg - tile_m * grid_n;
    const int atom = blockIdx.z;

    const ushort_t* Ab = A  + (size_t)tile_m * BMc * K;
    const ushort_t* Bb = Bm + ((size_t)atom * N + (size_t)tile_n * BNc) * K;

    const int tid  = threadIdx.x;
    const int lane = tid & 63;
    const int wave = tid >> 6;
    const int arow0 = (wave / WN) * (BMc / WM);
    const int brow0 = (wave % WN) * (BNc / WN);

    f32x4 acc[FM][FN];
    #pragma unroll
    for (int i = 0; i < FM; i++)
        #pragma unroll
        for (int j = 0; j < FN; j++)
            acc[i][j] = (f32x4){0.f, 0.f, 0.f, 0.f};

    const int nkt = K >> 6;

    stage64<BMc, NT>(Ab, K, 0, A0, tid);
    stage64<BNc, NT>(Bb, K, 0, B0, tid);
    asm volatile("s_waitcnt vmcnt(0)" ::: "memory");
    __syncthreads();

    for (int t = 0; t < nkt; t += 2) {
        stage64<BMc, NT>(Ab, K, (t + 1) << 6, A1, tid);
        stage64<BNc, NT>(Bb, K, (t + 1) << 6, B1, tid);
        compute64<FM, FN>(A0, B0, arow0, brow0, lane, acc);
        asm volatile("s_waitcnt vmcnt(0)" ::: "memory");
        __syncthreads();
        if (t + 2 < nkt) {
            stage64<BMc, NT>(Ab, K, (t + 2) << 6, A0, tid);
            stage64<BNc, NT>(Bb, K, (t + 2) << 6, B0, tid);
        }
        compute64<FM, FN>(A1, B1, arow0, brow0, lane, acc);
        asm volatile("s_waitcnt vmcnt(0)" ::: "memory");
        __syncthreads();
    }

    const int frow = lane & 15;
    const int fq   = lane >> 4;
    #pragma unroll
    for (int mi = 0; mi < FM; mi++) {
        #pragma unroll
        for (int ni = 0; ni < FN; ni++) {
            int n = tile_n * BNc + brow0 + ni * 16 + frow;
            float bn;
            if constexpr (MODE == 2) bn = bias[atom * H_ + n];
            else                     bn = bias[atom * D_ + n];
            #pragma unroll
            for (int rr = 0; rr < 4; rr++) {
                int m = tile_m * BMc + arow0 + mi * 16 + fq * 4 + rr;
                float v = acc[mi][ni][rr];
                if constexpr (MODE == 2) {
                    if (selIdx[m] == atom)
                        outB[(size_t)m * N + n] = f2bf(gelu_fast(v + bn));
                } else { // MODE 3
                    if (selIdx[m] == atom) {
                        int b = m / NCLS, nn = m - b * NCLS;
                        outF[(size_t)(b * SEQ + nn) * D_ + n] = (v + bn) * wgt[m];
                    }
                }
            }
        }
    }
}

// ---------------------------------------------------------------------------
// Launch
// ---------------------------------------------------------------------------
extern "C" void kernel_launch(void* const* d_in, const int* in_sizes, int n_in,
                              void* d_out, int out_size, void* d_ws, size_t ws_size,
                              hipStream_t stream) {
    const float* x   = (const float*)d_in[0];
    const float* w1  = (const float*)d_in[1];
    const float* b1  = (const float*)d_in[2];
    const float* w2  = (const float*)d_in[3];
    const float* b2  = (const float*)d_in[4];
    const float* gd  = (const float*)d_in[5];
    const float* aiw = (const float*)d_in[6];
    const float* aib = (const float*)d_in[7];
    const float* aow = (const float*)d_in[8];
    const float* aob = (const float*)d_in[9];
    float* out = (float*)d_out;

    char* ws = (char*)d_ws;
    ushort_t* Xp   = (ushort_t*)ws; ws += (size_t)NPATCH * D_ * 2;
    ushort_t* W1b  = (ushort_t*)ws; ws += (size_t)H_ * D_ * 2;
    ushort_t* W2b  = (ushort_t*)ws; ws += (size_t)D_ * H_ * 2;
    ushort_t* H1   = (ushort_t*)ws; ws += (size_t)NPATCH * H_ * 2;
    ushort_t* CLSb = (ushort_t*)ws; ws += (size_t)NPAIR * D_ * 2;
    ushort_t* AIWb = (ushort_t*)ws; ws += (size_t)NATOMS * H_ * D_ * 2;
    ushort_t* AOWb = (ushort_t*)ws; ws += (size_t)NATOMS * D_ * H_ * 2;
    ushort_t* HID  = (ushort_t*)ws; ws += (size_t)NPAIR * H_ * 2;
    int*   SRC = (int*)ws;   ws += NPAIR * 4;
    int*   DST = (int*)ws;   ws += NPAIR * 4;
    float* WGT = (float*)ws; ws += NPAIR * 4;

    // conversions
    split_x_kernel<<<(B_ * SEQ * D_ / 4 + 255) / 256, 256, 0, stream>>>(x, Xp, CLSb);
    cvt4_kernel<<<(H_ * D_ / 4 + 255) / 256, 256, 0, stream>>>(w1, W1b, H_ * D_);
    cvt4_kernel<<<(D_ * H_ / 4 + 255) / 256, 256, 0, stream>>>(w2, W2b, D_ * H_);
    cvt4_kernel<<<(NATOMS * H_ * D_ / 4 + 255) / 256, 256, 0, stream>>>(aiw, AIWb, NATOMS * H_ * D_);
    cvt4_kernel<<<(NATOMS * D_ * H_ / 4 + 255) / 256, 256, 0, stream>>>(aow, AOWb, NATOMS * D_ * H_);
    gate_kernel<<<NPAIR, 64, 0, stream>>>(x, gd, SRC, DST, WGT);

    // patch MLP: read-ahead pipelined kernels.
    // GEMM0: 256x256 (588 blocks).  GEMM1: 128x256 (294 blocks).
    gemm8p<0, 256><<<dim3(NPATCH / 256 * (H_ / 256), 1, 1), 512, 0, stream>>>(
        Xp, W1b, H_, D_, H_ / 256, b1, nullptr, H1);
    gemm8p<1, 128><<<dim3(NPATCH / 128 * (D_ / 256), 1, 1), 512, 0, stream>>>(
        H1, W2b, D_, H_, D_ / 256, b2, out, nullptr);

    // cls path: dense all-atom GEMMs with masked epilogue scatter (round-3 proven)
    gemm2p<2, 64, 128, 1, 2><<<dim3(NPAIR / 64 * (H_ / 128), 1, NATOMS), 128, 0, stream>>>(
        CLSb, AIWb, H_, D_, H_ / 128, aib, nullptr, HID, SRC, nullptr);
    gemm2p<3, 64, 128, 1, 2><<<dim3(NPAIR / 64 * (D_ / 128), 1, NATOMS), 128, 0, stream>>>(
        HID, AOWb, D_, H_, D_ / 128, aob, out, nullptr, DST, WGT);
}

// Round 8
// 326.612 us; speedup vs baseline: 1.2080x; 1.0495x over previous
//
#include <hip/hip_runtime.h>
#include <hip/hip_bf16.h>
#include <stdint.h>

// ---------------------------------------------------------------------------
// Problem constants
// ---------------------------------------------------------------------------
#define NCLS   6
#define NATOMS 5
#define B_     64
#define P_     196
#define D_     768
#define H_     3072
#define SEQ    (NCLS + P_)        // 202
#define NPATCH (B_ * P_)          // 12544
#define NPAIR  (B_ * NCLS)        // 384

typedef unsigned short ushort_t;
typedef __attribute__((ext_vector_type(8))) short  bf16x8;
typedef __attribute__((ext_vector_type(4))) float  f32x4;

// ---------------------------------------------------------------------------
// Helpers
// ---------------------------------------------------------------------------
// fast tanh-form GELU (max abs err ~1e-3; threshold budget 3.98e-2)
__device__ __forceinline__ float gelu_fast(float x) {
    float x2 = x * x;
    float y  = x * (1.59576912f + 0.07135482f * x2);
    float e  = __expf(y);
    return x * e / (e + 1.0f);
}

__device__ __forceinline__ ushort_t f2bf(float f) {
    uint32_t u = __builtin_bit_cast(uint32_t, f);
    u = (u + 0x7fffu + ((u >> 16) & 1u)) >> 16;
    return (ushort_t)u;
}

__device__ __forceinline__ void gload16(const ushort_t* g, ushort_t* l) {
    __builtin_amdgcn_global_load_lds(
        (const __attribute__((address_space(1))) uint32_t*)g,
        (__attribute__((address_space(3))) uint32_t*)l,
        16, 0, 0);
}

// ---------------------------------------------------------------------------
// fp32 -> bf16 conversion kernels
// ---------------------------------------------------------------------------
__global__ void cvt4_kernel(const float* __restrict__ in, ushort_t* __restrict__ out, int n) {
    int i = (blockIdx.x * blockDim.x + threadIdx.x) * 4;
    if (i >= n) return;
    float4 v = *(const float4*)(in + i);
    ushort4 o;
    o.x = f2bf(v.x); o.y = f2bf(v.y); o.z = f2bf(v.z); o.w = f2bf(v.w);
    *(ushort4*)(out + i) = o;
}

__global__ void split_x_kernel(const float* __restrict__ x,
                               ushort_t* __restrict__ xp,
                               ushort_t* __restrict__ cls) {
    int i = (blockIdx.x * blockDim.x + threadIdx.x) * 4;
    const int total = B_ * SEQ * D_;
    if (i >= total) return;
    int row = i / D_;
    int col = i - row * D_;
    int b = row / SEQ, s = row - b * SEQ;
    float4 v = *(const float4*)(x + i);
    ushort4 o;
    o.x = f2bf(v.x); o.y = f2bf(v.y); o.z = f2bf(v.z); o.w = f2bf(v.w);
    if (s < NCLS) {
        *(ushort4*)(cls + (size_t)(b * NCLS + s) * D_ + col) = o;
    } else {
        *(ushort4*)(xp + (size_t)(b * P_ + (s - NCLS)) * D_ + col) = o;
    }
}

// ---------------------------------------------------------------------------
// Gate
// ---------------------------------------------------------------------------
__global__ void gate_kernel(const float* __restrict__ x, const float* __restrict__ gd,
                            int* __restrict__ src, int* __restrict__ dst,
                            float* __restrict__ wgt) {
    int r = blockIdx.x;
    int b = r / NCLS, n = r - b * NCLS;
    const float* xr = x + (size_t)(b * SEQ + n) * D_;
    const float* g  = gd + (size_t)n * D_;
    int lane = threadIdx.x;
    float s = 0.f;
    for (int k = lane; k < D_; k += 64) s += xr[k] * g[k];
    #pragma unroll
    for (int off = 32; off > 0; off >>= 1) s += __shfl_down(s, off, 64);
    if (lane == 0) {
        float logit = s;
        bool left = (logit >= 0.f);
        float p = 1.f / (1.f + expf(-logit));
        float w = left ? p : (1.f - p);
        const int LK[NCLS] = {3, 4, 8, 9, 13, 14};
        const int RK[NCLS] = {15, 20, 16, 21, 17, 22};
        int key = left ? LK[n] : RK[n];
        src[r] = key / NATOMS;
        dst[r] = key % NATOMS;
        wgt[r] = w;
    }
}

// ===========================================================================
// 2-phase counted-vmcnt GEMM (patch MLP): C[m,n] = sum_k A[m,k]*B[n,k].
// BM x BN tile, 8 waves (2M x 4N), BK=64 as 2 K-halves of [rows x 32] bf16,
// double-buffered.  Per K-tile: stage whole next tile -> VMW(stage-count,
// keeps next tile's loads in flight, drains current) -> barrier -> 64-MFMA
// compute cluster (compiler-scheduled reads+MFMA, setprio-wrapped) -> barrier.
// vmcnt is per-wave; the barrier AFTER the VMW makes the drain cross-wave.
// WAR-safe: stage(t+1 -> buf^1) issues only after the trailing barrier of
// compute(t-1, buf^1).
//
// L2 cohort ordering: groups of 7 tile_m x 3 tile_n, gn-major, so an XCD's
// contiguous wg chunk keeps ~3 B-panels (1.2-2.4 MB) L2-hot while streaming
// A with 3x back-to-back reuse.  grid_m % 7 == 0, grid_n % 3 == 0.
//
// LDS swizzle (proven r6/r7, 0 bank conflicts): 16B-slot ^= (row>>1)&3,
// inverse-swizzled GLOBAL source + swizzled read address.
// ===========================================================================

template <int ROWS>
__device__ __forceinline__ void stage_half(const ushort_t* __restrict__ gpanel, int K,
                                           int kbase, ushort_t* lhalf, int tid) {
    constexpr int LOADS = ROWS * 4 / 512;
    #pragma unroll
    for (int l = 0; l < LOADS; ++l) {
        int c = (l << 9) + tid;
        int row = c >> 2;
        int col = ((c & 3) ^ ((row >> 1) & 3)) << 3;
        gload16(gpanel + (size_t)row * K + kbase + col, lhalf + ((size_t)c << 3));
    }
}

#define BAR     asm volatile("s_barrier" ::: "memory")
#define VMW(N)  asm volatile("s_waitcnt vmcnt(" #N ")" ::: "memory")
// per-wave stage instrs per K-tile = BM/64 + BN/64
#define VMW_T   do { if constexpr (BM == 256) { VMW(8); } else { VMW(4); } } while (0)

#define STAGE_TILE(T, DB) \
    stage_half<BM>(Ab, K, ((T) << 6),      &LA[DB][0][0], tid); \
    stage_half<BN>(Bb, K, ((T) << 6),      &LB[DB][0][0], tid); \
    stage_half<BM>(Ab, K, ((T) << 6) + 32, &LA[DB][1][0], tid); \
    stage_half<BN>(Bb, K, ((T) << 6) + 32, &LB[DB][1][0], tid);

// full K-tile compute: 2 ks x 2 mh x FMH x FN MFMA, reads + MFMA left to the
// compiler's scheduler (all LDS indices compile-time given literal DB).
#define COMPUTE(DB) do { \
    __builtin_amdgcn_s_setprio(1); \
    _Pragma("unroll") \
    for (int ks = 0; ks < 2; ++ks) { \
        bf16x8 bfr[FN]; \
        _Pragma("unroll") \
        for (int f = 0; f < FN; ++f) \
            bfr[f] = *(const bf16x8*)(&LB[DB][ks][bbase + f * 512]); \
        _Pragma("unroll") \
        for (int mh = 0; mh < 2; ++mh) { \
            bf16x8 afr[FMH]; \
            _Pragma("unroll") \
            for (int f = 0; f < FMH; ++f) \
                afr[f] = *(const bf16x8*)(&LA[DB][ks][abase + mh * (BM * 8) + f * 512]); \
            _Pragma("unroll") \
            for (int mi = 0; mi < FMH; ++mi) \
                _Pragma("unroll") \
                for (int ni = 0; ni < FN; ++ni) \
                    acc[mh * FMH + mi][ni] = __builtin_amdgcn_mfma_f32_16x16x32_bf16( \
                        afr[mi], bfr[ni], acc[mh * FMH + mi][ni], 0, 0, 0); \
        } \
    } \
    __builtin_amdgcn_s_setprio(0); \
    __builtin_amdgcn_sched_barrier(0); \
} while (0)

// MODE 0: H1 = bf16(gelu(acc + bias[n]))          (patch layer 1)
// MODE 1: out[(b*SEQ+NCLS+p)*D_+n] = acc+bias[n]  (patch layer 2)
template <int MODE, int BM, int BN, int MINW>
__global__ __launch_bounds__(512, MINW)
void gemm2s(const ushort_t* __restrict__ A, const ushort_t* __restrict__ Bm,
            int N, int K, int grid_m, int grid_n,
            const float* __restrict__ bias,
            float* __restrict__ outF, ushort_t* __restrict__ outB) {
    constexpr int FMH = BM / 128;    // A-frags per mh-half (2 or 1)... BM=256->2? no:
    // wave rows = BM/2; mh halves it again; frags = BM/2/2/16 = BM/64
    constexpr int FMH_ = BM / 64;    // actual frags per mh (4 for 256, 2 for 128)
    #undef  FMH
    #define FMH FMH_
    constexpr int FN = BN / 64;      // B-frags per wave (4 for 256, 2 for 128)

    __shared__ __align__(16) ushort_t LA[2][2][BM * 32];
    __shared__ __align__(16) ushort_t LB[2][2][BN * 32];

    // bijective XCD-chunk swizzle (m204)
    const int nwg = gridDim.x;
    int bid = blockIdx.x;
    int q = nwg >> 3, r = nwg & 7;
    int xcd = bid & 7, slot = bid >> 3;
    int wg = (xcd < r ? xcd * (q + 1) : r * (q + 1) + (xcd - r) * q) + slot;
    // L2 cohort decode: groups of 7m x 3n, gn-major
    int per_col = (grid_m / 7) * 21;
    int gn = wg / per_col;  int r1 = wg - gn * per_col;
    int gm = r1 / 21;       int ii = r1 - gm * 21;
    int tile_m = gm * 7 + ii / 3;
    int tile_n = gn * 3 + (ii - (ii / 3) * 3);

    const ushort_t* Ab = A  + (size_t)tile_m * BM * K;
    const ushort_t* Bb = Bm + (size_t)tile_n * BN * K;

    const int tid  = threadIdx.x;
    const int lane = tid & 63;
    const int wave = tid >> 6;
    const int wr = wave >> 2;   // 0..1 : A rows [wr*BM/2, +BM/2)
    const int wc = wave & 3;    // 0..3 : B rows [wc*BN/4, +BN/4)

    const int frow = lane & 15;
    const int fsl  = lane >> 4; // 16B-slot (k-offset) within 32-col half
    const int rbase = frow * 32 + ((fsl ^ ((frow >> 1) & 3)) << 3);
    const int abase = wr * (BM * 16) + rbase;   // + mh*(BM*8) + mi*512
    const int bbase = wc * (BN * 8) + rbase;    // + ni*512

    f32x4 acc[2 * FMH][FN];
    #pragma unroll
    for (int i = 0; i < 2 * FMH; i++)
        #pragma unroll
        for (int j = 0; j < FN; j++)
            acc[i][j] = (f32x4){0.f, 0.f, 0.f, 0.f};

    const int nkt = K >> 6;   // 12 or 48: even, >= 4

    STAGE_TILE(0, 0)
    for (int tb = 0; tb < (nkt >> 1) - 1; ++tb) {
        STAGE_TILE(2 * tb + 1, 1)
        VMW_T; BAR;
        COMPUTE(0);
        BAR;
        STAGE_TILE(2 * tb + 2, 0)
        VMW_T; BAR;
        COMPUTE(1);
        BAR;
    }
    STAGE_TILE(nkt - 1, 1)
    VMW_T; BAR;
    COMPUTE(0);
    BAR;
    VMW(0); BAR;
    COMPUTE(1);

    // epilogue: C/D layout col = lane&15, row = (lane>>4)*4 + reg
    const int fq = lane >> 4;
    #pragma unroll
    for (int mi = 0; mi < 2 * FMH; mi++) {
        #pragma unroll
        for (int ni = 0; ni < FN; ni++) {
            int n = tile_n * BN + wc * (BN / 4) + ni * 16 + frow;
            float bn = bias[n];
            #pragma unroll
            for (int rr = 0; rr < 4; rr++) {
                int m = tile_m * BM + wr * (BM / 2) + mi * 16 + fq * 4 + rr;
                float v = acc[mi][ni][rr];
                if constexpr (MODE == 0) {
                    outB[(size_t)m * N + n] = f2bf(gelu_fast(v + bn));
                } else {
                    int b = m / P_, p = m - b * P_;
                    outF[(size_t)(b * SEQ + NCLS + p) * D_ + n] = v + bn;
                }
            }
        }
    }
    #undef FMH
}

// ---------------------------------------------------------------------------
// cls-path GEMM: round-3 2-phase double-buffered structure (proven), BK=64.
// ---------------------------------------------------------------------------
template <int ROWS, int NT>
__device__ __forceinline__ void stage64(const ushort_t* __restrict__ gbase, int K,
                                        int k0, ushort_t* lds, int tid) {
    constexpr int LOADS = ROWS * 64 * 2 / (NT * 16);
    #pragma unroll
    for (int l = 0; l < LOADS; ++l) {
        int c = l * NT + tid;
        gload16(gbase + (size_t)(c >> 3) * K + k0 + ((c & 7) << 3),
                lds + (size_t)c * 8);
    }
}

template <int FM, int FN>
__device__ __forceinline__ void compute64(const ushort_t* sA, const ushort_t* sB,
                                          int arow0, int brow0, int lane,
                                          f32x4 (&acc)[FM][FN]) {
    const int frow = lane & 15;
    const int fcol = (lane >> 4) * 8;
    #pragma unroll
    for (int ks = 0; ks < 2; ++ks) {
        bf16x8 af[FM], bfv[FN];
        #pragma unroll
        for (int mi = 0; mi < FM; ++mi)
            af[mi] = *(const bf16x8*)(sA + (size_t)(arow0 + mi * 16 + frow) * 64 + ks * 32 + fcol);
        #pragma unroll
        for (int ni = 0; ni < FN; ++ni)
            bfv[ni] = *(const bf16x8*)(sB + (size_t)(brow0 + ni * 16 + frow) * 64 + ks * 32 + fcol);
        #pragma unroll
        for (int mi = 0; mi < FM; ++mi)
            #pragma unroll
            for (int ni = 0; ni < FN; ++ni)
                acc[mi][ni] = __builtin_amdgcn_mfma_f32_16x16x32_bf16(
                    af[mi], bfv[ni], acc[mi][ni], 0, 0, 0);
    }
}

// MODE 2: if src[m]==atom: HID = bf16(gelu(acc + bias[atom*H_+n]))
// MODE 3: if dst[m]==atom: out[(b*SEQ+nn)*D_+n] = (acc + bias[atom*D_+n])*wgt[m]
template <int MODE, int BMc, int BNc, int WM, int WN>
__global__ __launch_bounds__(WM * WN * 64, 2)
void gemm2p(const ushort_t* __restrict__ A,
            const ushort_t* __restrict__ Bm,
            int N, int K, int grid_n,
            const float* __restrict__ bias,
            float* __restrict__ outF,
            ushort_t* __restrict__ outB,
            const int* __restrict__ selIdx,
            const float* __restrict__ wgt) {
    constexpr int NT = WM * WN * 64;
    constexpr int FM = BMc / WM / 16;
    constexpr int FN = BNc / WN / 16;

    __shared__ __align__(16) ushort_t A0[BMc * 64], A1[BMc * 64];
    __shared__ __align__(16) ushort_t B0[BNc * 64], B1[BNc * 64];

    const int nwg = gridDim.x;
    int bid = blockIdx.x;
    int q = nwg >> 3, r = nwg & 7;
    int xcd = bid & 7, slot = bid >> 3;
    int wg = (xcd < r ? xcd * (q + 1) : r * (q + 1) + (xcd - r) * q) + slot;
    int tile_m = wg / grid_n;
    int tile_n = wg - tile_m * grid_n;
    const int atom = blockIdx.z;

    const ushort_t* Ab = A  + (size_t)tile_m * BMc * K;
    const ushort_t* Bb = Bm + ((size_t)atom * N + (size_t)tile_n * BNc) * K;

    const int tid  = threadIdx.x;
    const int lane = tid & 63;
    const int wave = tid >> 6;
    const int arow0 = (wave / WN) * (BMc / WM);
    const int brow0 = (wave % WN) * (BNc / WN);

    f32x4 acc[FM][FN];
    #pragma unroll
    for (int i = 0; i < FM; i++)
        #pragma unroll
        for (int j = 0; j < FN; j++)
            acc[i][j] = (f32x4){0.f, 0.f, 0.f, 0.f};

    const int nkt = K >> 6;

    stage64<BMc, NT>(Ab, K, 0, A0, tid);
    stage64<BNc, NT>(Bb, K, 0, B0, tid);
    asm volatile("s_waitcnt vmcnt(0)" ::: "memory");
    __syncthreads();

    for (int t = 0; t < nkt; t += 2) {
        stage64<BMc, NT>(Ab, K, (t + 1) << 6, A1, tid);
        stage64<BNc, NT>(Bb, K, (t + 1) << 6, B1, tid);
        compute64<FM, FN>(A0, B0, arow0, brow0, lane, acc);
        asm volatile("s_waitcnt vmcnt(0)" ::: "memory");
        __syncthreads();
        if (t + 2 < nkt) {
            stage64<BMc, NT>(Ab, K, (t + 2) << 6, A0, tid);
            stage64<BNc, NT>(Bb, K, (t + 2) << 6, B0, tid);
        }
        compute64<FM, FN>(A1, B1, arow0, brow0, lane, acc);
        asm volatile("s_waitcnt vmcnt(0)" ::: "memory");
        __syncthreads();
    }

    const int frow = lane & 15;
    const int fq   = lane >> 4;
    #pragma unroll
    for (int mi = 0; mi < FM; mi++) {
        #pragma unroll
        for (int ni = 0; ni < FN; ni++) {
            int n = tile_n * BNc + brow0 + ni * 16 + frow;
            float bn;
            if constexpr (MODE == 2) bn = bias[atom * H_ + n];
            else                     bn = bias[atom * D_ + n];
            #pragma unroll
            for (int rr = 0; rr < 4; rr++) {
                int m = tile_m * BMc + arow0 + mi * 16 + fq * 4 + rr;
                float v = acc[mi][ni][rr];
                if constexpr (MODE == 2) {
                    if (selIdx[m] == atom)
                        outB[(size_t)m * N + n] = f2bf(gelu_fast(v + bn));
                } else { // MODE 3
                    if (selIdx[m] == atom) {
                        int b = m / NCLS, nn = m - b * NCLS;
                        outF[(size_t)(b * SEQ + nn) * D_ + n] = (v + bn) * wgt[m];
                    }
                }
            }
        }
    }
}

// ---------------------------------------------------------------------------
// Launch
// ---------------------------------------------------------------------------
extern "C" void kernel_launch(void* const* d_in, const int* in_sizes, int n_in,
                              void* d_out, int out_size, void* d_ws, size_t ws_size,
                              hipStream_t stream) {
    const float* x   = (const float*)d_in[0];
    const float* w1  = (const float*)d_in[1];
    const float* b1  = (const float*)d_in[2];
    const float* w2  = (const float*)d_in[3];
    const float* b2  = (const float*)d_in[4];
    const float* gd  = (const float*)d_in[5];
    const float* aiw = (const float*)d_in[6];
    const float* aib = (const float*)d_in[7];
    const float* aow = (const float*)d_in[8];
    const float* aob = (const float*)d_in[9];
    float* out = (float*)d_out;

    char* ws = (char*)d_ws;
    ushort_t* Xp   = (ushort_t*)ws; ws += (size_t)NPATCH * D_ * 2;
    ushort_t* W1b  = (ushort_t*)ws; ws += (size_t)H_ * D_ * 2;
    ushort_t* W2b  = (ushort_t*)ws; ws += (size_t)D_ * H_ * 2;
    ushort_t* H1   = (ushort_t*)ws; ws += (size_t)NPATCH * H_ * 2;
    ushort_t* CLSb = (ushort_t*)ws; ws += (size_t)NPAIR * D_ * 2;
    ushort_t* AIWb = (ushort_t*)ws; ws += (size_t)NATOMS * H_ * D_ * 2;
    ushort_t* AOWb = (ushort_t*)ws; ws += (size_t)NATOMS * D_ * H_ * 2;
    ushort_t* HID  = (ushort_t*)ws; ws += (size_t)NPAIR * H_ * 2;
    int*   SRC = (int*)ws;   ws += NPAIR * 4;
    int*   DST = (int*)ws;   ws += NPAIR * 4;
    float* WGT = (float*)ws; ws += NPAIR * 4;

    // conversions
    split_x_kernel<<<(B_ * SEQ * D_ / 4 + 255) / 256, 256, 0, stream>>>(x, Xp, CLSb);
    cvt4_kernel<<<(H_ * D_ / 4 + 255) / 256, 256, 0, stream>>>(w1, W1b, H_ * D_);
    cvt4_kernel<<<(D_ * H_ / 4 + 255) / 256, 256, 0, stream>>>(w2, W2b, D_ * H_);
    cvt4_kernel<<<(NATOMS * H_ * D_ / 4 + 255) / 256, 256, 0, stream>>>(aiw, AIWb, NATOMS * H_ * D_);
    cvt4_kernel<<<(NATOMS * D_ * H_ / 4 + 255) / 256, 256, 0, stream>>>(aow, AOWb, NATOMS * D_ * H_);
    gate_kernel<<<NPAIR, 64, 0, stream>>>(x, gd, SRC, DST, WGT);

    // patch MLP: 2-phase counted-vmcnt kernels with L2 cohorts.
    // GEMM0: 256x256, grid 49x12 = 588, 1 blk/CU.
    // GEMM1: 128x128, grid 98x6 = 588, 64KB LDS -> 2 blk/CU (TLP vs misses).
    gemm2s<0, 256, 256, 2><<<dim3(588, 1, 1), 512, 0, stream>>>(
        Xp, W1b, H_, D_, 49, 12, b1, nullptr, H1);
    gemm2s<1, 128, 128, 4><<<dim3(588, 1, 1), 512, 0, stream>>>(
        H1, W2b, D_, H_, 98, 6, b2, out, nullptr);

    // cls path: dense all-atom GEMMs with masked epilogue scatter (round-3 proven)
    gemm2p<2, 64, 128, 1, 2><<<dim3(NPAIR / 64 * (H_ / 128), 1, NATOMS), 128, 0, stream>>>(
        CLSb, AIWb, H_, D_, H_ / 128, aib, nullptr, HID, SRC, nullptr);
    gemm2p<3, 64, 128, 1, 2><<<dim3(NPAIR / 64 * (D_ / 128), 1, NATOMS), 128, 0, stream>>>(
        HID, AOWb, D_, H_, D_ / 128, aob, out, nullptr, DST, WGT);
}

// Round 9
// 296.714 us; speedup vs baseline: 1.3298x; 1.1008x over previous
//
#include <hip/hip_runtime.h>
#include <hip/hip_bf16.h>
#include <stdint.h>

// ---------------------------------------------------------------------------
// Problem constants
// ---------------------------------------------------------------------------
#define NCLS   6
#define NATOMS 5
#define B_     64
#define P_     196
#define D_     768
#define H_     3072
#define SEQ    (NCLS + P_)        // 202
#define NPATCH (B_ * P_)          // 12544
#define NPAIR  (B_ * NCLS)        // 384

typedef unsigned short ushort_t;
typedef __attribute__((ext_vector_type(8))) short  bf16x8;
typedef __attribute__((ext_vector_type(4))) float  f32x4;

// ---------------------------------------------------------------------------
// Helpers
// ---------------------------------------------------------------------------
// fast tanh-form GELU (max abs err ~1e-3; threshold budget 3.98e-2)
__device__ __forceinline__ float gelu_fast(float x) {
    float x2 = x * x;
    float y  = x * (1.59576912f + 0.07135482f * x2);
    float e  = __expf(y);
    return x * e / (e + 1.0f);
}

__device__ __forceinline__ ushort_t f2bf(float f) {
    uint32_t u = __builtin_bit_cast(uint32_t, f);
    u = (u + 0x7fffu + ((u >> 16) & 1u)) >> 16;
    return (ushort_t)u;
}

__device__ __forceinline__ void gload16(const ushort_t* g, ushort_t* l) {
    __builtin_amdgcn_global_load_lds(
        (const __attribute__((address_space(1))) uint32_t*)g,
        (__attribute__((address_space(3))) uint32_t*)l,
        16, 0, 0);
}

// ---------------------------------------------------------------------------
// fp32 -> bf16 conversion kernels
// ---------------------------------------------------------------------------
// one fused kernel for the four weight tensors (region dispatch by blockIdx)
#define CVT_B1 (H_ * D_ / 1024)              // 2304 blocks for w1
#define CVT_B2 (CVT_B1 + D_ * H_ / 1024)     // + w2
#define CVT_B3 (CVT_B2 + NATOMS * H_ * D_ / 1024)
#define CVT_B4 (CVT_B3 + NATOMS * D_ * H_ / 1024)

__global__ void cvt_all_kernel(const float* __restrict__ w1, ushort_t* __restrict__ o1,
                               const float* __restrict__ w2, ushort_t* __restrict__ o2,
                               const float* __restrict__ aiw, ushort_t* __restrict__ o3,
                               const float* __restrict__ aow, ushort_t* __restrict__ o4) {
    int bid = blockIdx.x;
    const float* src; ushort_t* dst; int i;
    if (bid < CVT_B1)      { src = w1;  dst = o1; i = bid * 1024; }
    else if (bid < CVT_B2) { src = w2;  dst = o2; i = (bid - CVT_B1) * 1024; }
    else if (bid < CVT_B3) { src = aiw; dst = o3; i = (bid - CVT_B2) * 1024; }
    else                   { src = aow; dst = o4; i = (bid - CVT_B3) * 1024; }
    i += threadIdx.x * 4;
    float4 v = *(const float4*)(src + i);
    ushort4 o;
    o.x = f2bf(v.x); o.y = f2bf(v.y); o.z = f2bf(v.z); o.w = f2bf(v.w);
    *(ushort4*)(dst + i) = o;
}

__global__ void split_x_kernel(const float* __restrict__ x,
                               ushort_t* __restrict__ xp,
                               ushort_t* __restrict__ cls) {
    int i = (blockIdx.x * blockDim.x + threadIdx.x) * 4;
    const int total = B_ * SEQ * D_;
    if (i >= total) return;
    int row = i / D_;
    int col = i - row * D_;
    int b = row / SEQ, s = row - b * SEQ;
    float4 v = *(const float4*)(x + i);
    ushort4 o;
    o.x = f2bf(v.x); o.y = f2bf(v.y); o.z = f2bf(v.z); o.w = f2bf(v.w);
    if (s < NCLS) {
        *(ushort4*)(cls + (size_t)(b * NCLS + s) * D_ + col) = o;
    } else {
        *(ushort4*)(xp + (size_t)(b * P_ + (s - NCLS)) * D_ + col) = o;
    }
}

// ---------------------------------------------------------------------------
// Gate
// ---------------------------------------------------------------------------
__global__ void gate_kernel(const float* __restrict__ x, const float* __restrict__ gd,
                            int* __restrict__ src, int* __restrict__ dst,
                            float* __restrict__ wgt) {
    int r = blockIdx.x;
    int b = r / NCLS, n = r - b * NCLS;
    const float* xr = x + (size_t)(b * SEQ + n) * D_;
    const float* g  = gd + (size_t)n * D_;
    int lane = threadIdx.x;
    float s = 0.f;
    for (int k = lane; k < D_; k += 64) s += xr[k] * g[k];
    #pragma unroll
    for (int off = 32; off > 0; off >>= 1) s += __shfl_down(s, off, 64);
    if (lane == 0) {
        float logit = s;
        bool left = (logit >= 0.f);
        float p = 1.f / (1.f + expf(-logit));
        float w = left ? p : (1.f - p);
        const int LK[NCLS] = {3, 4, 8, 9, 13, 14};
        const int RK[NCLS] = {15, 20, 16, 21, 17, 22};
        int key = left ? LK[n] : RK[n];
        src[r] = key / NATOMS;
        dst[r] = key % NATOMS;
        wgt[r] = w;
    }
}

// ===========================================================================
// 2-phase counted-vmcnt GEMM (patch MLP): C[m,n] = sum_k A[m,k]*B[n,k].
// 128x128 tile, 8 waves (2M x 4N), 64 KB LDS -> 2 blocks/CU (the decisive
// lever per r3-vs-r6/7/8: a second independent block covers VMW stalls).
// BK=64 as 2 K-halves of [128 x 32] bf16, double-buffered.  Per K-tile:
// stage next tile (4 gload_lds/thread) -> VMW(4) (keeps next tile in
// flight, drains current) -> barrier -> 32-MFMA cluster -> barrier.
// L2 cohorts: 7m x 3n groups, gn-major (grid_m % 7 == 0, grid_n % 3 == 0).
// LDS swizzle (0 conflicts, r6-r8): 16B-slot ^= (row>>1)&3, inverse-swizzled
// GLOBAL source (linear gload_lds dest) + swizzled read address.
// ===========================================================================

template <int ROWS>
__device__ __forceinline__ void stage_half(const ushort_t* __restrict__ gpanel, int K,
                                           int kbase, ushort_t* lhalf, int tid) {
    constexpr int LOADS = ROWS * 4 / 512;
    #pragma unroll
    for (int l = 0; l < LOADS; ++l) {
        int c = (l << 9) + tid;
        int row = c >> 2;
        int col = ((c & 3) ^ ((row >> 1) & 3)) << 3;
        gload16(gpanel + (size_t)row * K + kbase + col, lhalf + ((size_t)c << 3));
    }
}

#define BAR     asm volatile("s_barrier" ::: "memory")
#define VMW(N)  asm volatile("s_waitcnt vmcnt(" #N ")" ::: "memory")
// per-wave stage instrs per K-tile = (BM + BN) / 128  (NT = 512)
#define VMW_T   do { if constexpr (BM + BN == 512) { VMW(8); } else { VMW(4); } } while (0)

#define STAGE_TILE(T, DB) \
    stage_half<BM>(Ab, K, ((T) << 6),      &LA[DB][0][0], tid); \
    stage_half<BN>(Bb, K, ((T) << 6),      &LB[DB][0][0], tid); \
    stage_half<BM>(Ab, K, ((T) << 6) + 32, &LA[DB][1][0], tid); \
    stage_half<BN>(Bb, K, ((T) << 6) + 32, &LB[DB][1][0], tid);

// full K-tile compute: 2 ks x 2 mh x FMH x FN MFMA, reads + MFMA left to the
// compiler's scheduler (all LDS indices compile-time given literal DB).
#define COMPUTE(DB) do { \
    __builtin_amdgcn_s_setprio(1); \
    _Pragma("unroll") \
    for (int ks = 0; ks < 2; ++ks) { \
        bf16x8 bfr[FN]; \
        _Pragma("unroll") \
        for (int f = 0; f < FN; ++f) \
            bfr[f] = *(const bf16x8*)(&LB[DB][ks][bbase + f * 512]); \
        _Pragma("unroll") \
        for (int mh = 0; mh < 2; ++mh) { \
            bf16x8 afr[FMH]; \
            _Pragma("unroll") \
            for (int f = 0; f < FMH; ++f) \
                afr[f] = *(const bf16x8*)(&LA[DB][ks][abase + mh * (BM * 8) + f * 512]); \
            _Pragma("unroll") \
            for (int mi = 0; mi < FMH; ++mi) \
                _Pragma("unroll") \
                for (int ni = 0; ni < FN; ++ni) \
                    acc[mh * FMH + mi][ni] = __builtin_amdgcn_mfma_f32_16x16x32_bf16( \
                        afr[mi], bfr[ni], acc[mh * FMH + mi][ni], 0, 0, 0); \
        } \
    } \
    __builtin_amdgcn_s_setprio(0); \
    __builtin_amdgcn_sched_barrier(0); \
} while (0)

// MODE 0: H1 = bf16(gelu(acc + bias[n]))          (patch layer 1)
// MODE 1: out[(b*SEQ+NCLS+p)*D_+n] = acc+bias[n]  (patch layer 2)
template <int MODE, int BM, int BN, int MINW>
__global__ __launch_bounds__(512, MINW)
void gemm2s(const ushort_t* __restrict__ A, const ushort_t* __restrict__ Bm,
            int N, int K, int grid_m, int grid_n,
            const float* __restrict__ bias,
            float* __restrict__ outF, ushort_t* __restrict__ outB) {
    constexpr int FMH = BM / 64;     // A-frags per mh half-row-block
    constexpr int FN  = BN / 64;     // B-frags per wave

    __shared__ __align__(16) ushort_t LA[2][2][BM * 32];
    __shared__ __align__(16) ushort_t LB[2][2][BN * 32];

    // bijective XCD-chunk swizzle (m204)
    const int nwg = gridDim.x;
    int bid = blockIdx.x;
    int q = nwg >> 3, r = nwg & 7;
    int xcd = bid & 7, slot = bid >> 3;
    int wg = (xcd < r ? xcd * (q + 1) : r * (q + 1) + (xcd - r) * q) + slot;
    // L2 cohort decode: groups of 7m x 3n, gn-major
    int per_col = (grid_m / 7) * 21;
    int gn = wg / per_col;  int r1 = wg - gn * per_col;
    int gm = r1 / 21;       int ii = r1 - gm * 21;
    int tile_m = gm * 7 + ii / 3;
    int tile_n = gn * 3 + (ii - (ii / 3) * 3);

    const ushort_t* Ab = A  + (size_t)tile_m * BM * K;
    const ushort_t* Bb = Bm + (size_t)tile_n * BN * K;

    const int tid  = threadIdx.x;
    const int lane = tid & 63;
    const int wave = tid >> 6;
    const int wr = wave >> 2;   // 0..1 : A rows [wr*BM/2, +BM/2)
    const int wc = wave & 3;    // 0..3 : B rows [wc*BN/4, +BN/4)

    const int frow = lane & 15;
    const int fsl  = lane >> 4; // 16B-slot (k-offset) within 32-col half
    const int rbase = frow * 32 + ((fsl ^ ((frow >> 1) & 3)) << 3);
    const int abase = wr * (BM * 16) + rbase;   // + mh*(BM*8) + mi*512
    const int bbase = wc * (BN * 8) + rbase;    // + ni*512

    f32x4 acc[2 * FMH][FN];
    #pragma unroll
    for (int i = 0; i < 2 * FMH; i++)
        #pragma unroll
        for (int j = 0; j < FN; j++)
            acc[i][j] = (f32x4){0.f, 0.f, 0.f, 0.f};

    const int nkt = K >> 6;   // 12 or 48: even, >= 4

    STAGE_TILE(0, 0)
    for (int tb = 0; tb < (nkt >> 1) - 1; ++tb) {
        STAGE_TILE(2 * tb + 1, 1)
        VMW_T; BAR;
        COMPUTE(0);
        BAR;
        STAGE_TILE(2 * tb + 2, 0)
        VMW_T; BAR;
        COMPUTE(1);
        BAR;
    }
    STAGE_TILE(nkt - 1, 1)
    VMW_T; BAR;
    COMPUTE(0);
    BAR;
    VMW(0); BAR;
    COMPUTE(1);

    // epilogue: C/D layout col = lane&15, row = (lane>>4)*4 + reg
    const int fq = lane >> 4;
    #pragma unroll
    for (int mi = 0; mi < 2 * FMH; mi++) {
        #pragma unroll
        for (int ni = 0; ni < FN; ni++) {
            int n = tile_n * BN + wc * (BN / 4) + ni * 16 + frow;
            float bn = bias[n];
            #pragma unroll
            for (int rr = 0; rr < 4; rr++) {
                int m = tile_m * BM + wr * (BM / 2) + mi * 16 + fq * 4 + rr;
                float v = acc[mi][ni][rr];
                if constexpr (MODE == 0) {
                    outB[(size_t)m * N + n] = f2bf(gelu_fast(v + bn));
                } else {
                    int b = m / P_, p = m - b * P_;
                    outF[(size_t)(b * SEQ + NCLS + p) * D_ + n] = v + bn;
                }
            }
        }
    }
}

// ---------------------------------------------------------------------------
// cls-path GEMM: round-3 2-phase double-buffered structure (proven), BK=64.
// ---------------------------------------------------------------------------
template <int ROWS, int NT>
__device__ __forceinline__ void stage64(const ushort_t* __restrict__ gbase, int K,
                                        int k0, ushort_t* lds, int tid) {
    constexpr int LOADS = ROWS * 64 * 2 / (NT * 16);
    #pragma unroll
    for (int l = 0; l < LOADS; ++l) {
        int c = l * NT + tid;
        gload16(gbase + (size_t)(c >> 3) * K + k0 + ((c & 7) << 3),
                lds + (size_t)c * 8);
    }
}

template <int FM, int FN>
__device__ __forceinline__ void compute64(const ushort_t* sA, const ushort_t* sB,
                                          int arow0, int brow0, int lane,
                                          f32x4 (&acc)[FM][FN]) {
    const int frow = lane & 15;
    const int fcol = (lane >> 4) * 8;
    #pragma unroll
    for (int ks = 0; ks < 2; ++ks) {
        bf16x8 af[FM], bfv[FN];
        #pragma unroll
        for (int mi = 0; mi < FM; ++mi)
            af[mi] = *(const bf16x8*)(sA + (size_t)(arow0 + mi * 16 + frow) * 64 + ks * 32 + fcol);
        #pragma unroll
        for (int ni = 0; ni < FN; ++ni)
            bfv[ni] = *(const bf16x8*)(sB + (size_t)(brow0 + ni * 16 + frow) * 64 + ks * 32 + fcol);
        #pragma unroll
        for (int mi = 0; mi < FM; ++mi)
            #pragma unroll
            for (int ni = 0; ni < FN; ++ni)
                acc[mi][ni] = __builtin_amdgcn_mfma_f32_16x16x32_bf16(
                    af[mi], bfv[ni], acc[mi][ni], 0, 0, 0);
    }
}

// MODE 2: if src[m]==atom: HID = bf16(gelu(acc + bias[atom*H_+n]))
// MODE 3: if dst[m]==atom: out[(b*SEQ+nn)*D_+n] = (acc + bias[atom*D_+n])*wgt[m]
template <int MODE, int BMc, int BNc, int WM, int WN>
__global__ __launch_bounds__(WM * WN * 64, 2)
void gemm2p(const ushort_t* __restrict__ A,
            const ushort_t* __restrict__ Bm,
            int N, int K, int grid_n,
            const float* __restrict__ bias,
            float* __restrict__ outF,
            ushort_t* __restrict__ outB,
            const int* __restrict__ selIdx,
            const float* __restrict__ wgt) {
    constexpr int NT = WM * WN * 64;
    constexpr int FM = BMc / WM / 16;
    constexpr int FN = BNc / WN / 16;

    __shared__ __align__(16) ushort_t A0[BMc * 64], A1[BMc * 64];
    __shared__ __align__(16) ushort_t B0[BNc * 64], B1[BNc * 64];

    const int nwg = gridDim.x;
    int bid = blockIdx.x;
    int q = nwg >> 3, r = nwg & 7;
    int xcd = bid & 7, slot = bid >> 3;
    int wg = (xcd < r ? xcd * (q + 1) : r * (q + 1) + (xcd - r) * q) + slot;
    int tile_m = wg / grid_n;
    int tile_n = wg - tile_m * grid_n;
    const int atom = blockIdx.z;

    const ushort_t* Ab = A  + (size_t)tile_m * BMc * K;
    const ushort_t* Bb = Bm + ((size_t)atom * N + (size_t)tile_n * BNc) * K;

    const int tid  = threadIdx.x;
    const int lane = tid & 63;
    const int wave = tid >> 6;
    const int arow0 = (wave / WN) * (BMc / WM);
    const int brow0 = (wave % WN) * (BNc / WN);

    f32x4 acc[FM][FN];
    #pragma unroll
    for (int i = 0; i < FM; i++)
        #pragma unroll
        for (int j = 0; j < FN; j++)
            acc[i][j] = (f32x4){0.f, 0.f, 0.f, 0.f};

    const int nkt = K >> 6;

    stage64<BMc, NT>(Ab, K, 0, A0, tid);
    stage64<BNc, NT>(Bb, K, 0, B0, tid);
    asm volatile("s_waitcnt vmcnt(0)" ::: "memory");
    __syncthreads();

    for (int t = 0; t < nkt; t += 2) {
        stage64<BMc, NT>(Ab, K, (t + 1) << 6, A1, tid);
        stage64<BNc, NT>(Bb, K, (t + 1) << 6, B1, tid);
        compute64<FM, FN>(A0, B0, arow0, brow0, lane, acc);
        asm volatile("s_waitcnt vmcnt(0)" ::: "memory");
        __syncthreads();
        if (t + 2 < nkt) {
            stage64<BMc, NT>(Ab, K, (t + 2) << 6, A0, tid);
            stage64<BNc, NT>(Bb, K, (t + 2) << 6, B0, tid);
        }
        compute64<FM, FN>(A1, B1, arow0, brow0, lane, acc);
        asm volatile("s_waitcnt vmcnt(0)" ::: "memory");
        __syncthreads();
    }

    const int frow = lane & 15;
    const int fq   = lane >> 4;
    #pragma unroll
    for (int mi = 0; mi < FM; mi++) {
        #pragma unroll
        for (int ni = 0; ni < FN; ni++) {
            int n = tile_n * BNc + brow0 + ni * 16 + frow;
            float bn;
            if constexpr (MODE == 2) bn = bias[atom * H_ + n];
            else                     bn = bias[atom * D_ + n];
            #pragma unroll
            for (int rr = 0; rr < 4; rr++) {
                int m = tile_m * BMc + arow0 + mi * 16 + fq * 4 + rr;
                float v = acc[mi][ni][rr];
                if constexpr (MODE == 2) {
                    if (selIdx[m] == atom)
                        outB[(size_t)m * N + n] = f2bf(gelu_fast(v + bn));
                } else { // MODE 3
                    if (selIdx[m] == atom) {
                        int b = m / NCLS, nn = m - b * NCLS;
                        outF[(size_t)(b * SEQ + nn) * D_ + n] = (v + bn) * wgt[m];
                    }
                }
            }
        }
    }
}

// ---------------------------------------------------------------------------
// Launch
// ---------------------------------------------------------------------------
extern "C" void kernel_launch(void* const* d_in, const int* in_sizes, int n_in,
                              void* d_out, int out_size, void* d_ws, size_t ws_size,
                              hipStream_t stream) {
    const float* x   = (const float*)d_in[0];
    const float* w1  = (const float*)d_in[1];
    const float* b1  = (const float*)d_in[2];
    const float* w2  = (const float*)d_in[3];
    const float* b2  = (const float*)d_in[4];
    const float* gd  = (const float*)d_in[5];
    const float* aiw = (const float*)d_in[6];
    const float* aib = (const float*)d_in[7];
    const float* aow = (const float*)d_in[8];
    const float* aob = (const float*)d_in[9];
    float* out = (float*)d_out;

    char* ws = (char*)d_ws;
    ushort_t* Xp   = (ushort_t*)ws; ws += (size_t)NPATCH * D_ * 2;
    ushort_t* W1b  = (ushort_t*)ws; ws += (size_t)H_ * D_ * 2;
    ushort_t* W2b  = (ushort_t*)ws; ws += (size_t)D_ * H_ * 2;
    ushort_t* H1   = (ushort_t*)ws; ws += (size_t)NPATCH * H_ * 2;
    ushort_t* CLSb = (ushort_t*)ws; ws += (size_t)NPAIR * D_ * 2;
    ushort_t* AIWb = (ushort_t*)ws; ws += (size_t)NATOMS * H_ * D_ * 2;
    ushort_t* AOWb = (ushort_t*)ws; ws += (size_t)NATOMS * D_ * H_ * 2;
    ushort_t* HID  = (ushort_t*)ws; ws += (size_t)NPAIR * H_ * 2;
    int*   SRC = (int*)ws;   ws += NPAIR * 4;
    int*   DST = (int*)ws;   ws += NPAIR * 4;
    float* WGT = (float*)ws; ws += NPAIR * 4;

    // conversions (weights fused into one launch)
    split_x_kernel<<<(B_ * SEQ * D_ / 4 + 255) / 256, 256, 0, stream>>>(x, Xp, CLSb);
    cvt_all_kernel<<<CVT_B4, 256, 0, stream>>>(w1, W1b, w2, W2b, aiw, AIWb, aow, AOWb);
    gate_kernel<<<NPAIR, 64, 0, stream>>>(x, gd, SRC, DST, WGT);

    // patch MLP: 128x128, 8 waves, 64KB LDS -> 2 blocks/CU, counted vmcnt,
    // swizzle, L2 cohorts.  GEMM0 grid 98x24 = 2352; GEMM1 grid 98x6 = 588.
    gemm2s<0, 128, 128, 4><<<dim3(2352, 1, 1), 512, 0, stream>>>(
        Xp, W1b, H_, D_, 98, 24, b1, nullptr, H1);
    gemm2s<1, 128, 128, 4><<<dim3(588, 1, 1), 512, 0, stream>>>(
        H1, W2b, D_, H_, 98, 6, b2, out, nullptr);

    // cls path: dense all-atom GEMMs with masked epilogue scatter (round-3 proven)
    gemm2p<2, 64, 128, 1, 2><<<dim3(NPAIR / 64 * (H_ / 128), 1, NATOMS), 128, 0, stream>>>(
        CLSb, AIWb, H_, D_, H_ / 128, aib, nullptr, HID, SRC, nullptr);
    gemm2p<3, 64, 128, 1, 2><<<dim3(NPAIR / 64 * (D_ / 128), 1, NATOMS), 128, 0, stream>>>(
        HID, AOWb, D_, H_, D_ / 128, aob, out, nullptr, DST, WGT);
}